// Round 10
// baseline (1250.747 us; speedup 1.0000x reference)
//
#include <hip/hip_runtime.h>
#include <hip/hip_bf16.h>
#include <math.h>

#define NN 50000
#define EE 800000
#define FF 32
#define HH 64
#define GG 2048
#define NLAYERS 4
#define EPSF 1e-6f
#define TILES 4

typedef __attribute__((ext_vector_type(8))) short short8;
typedef __attribute__((ext_vector_type(4))) float f32x4;
typedef __attribute__((ext_vector_type(4))) unsigned short us4;

__device__ __forceinline__ float elu_f(float x){ return x > 0.0f ? x : __expf(x) - 1.0f; }
__device__ __forceinline__ short f2bf_s(float x){
    __hip_bfloat16 h = __float2bfloat16(x);
    return *reinterpret_cast<short*>(&h);
}
__device__ __forceinline__ float bf2f(unsigned short u){
    unsigned int w = ((unsigned int)u) << 16;
    return *reinterpret_cast<float*>(&w);
}

// ---------------- in-degree count ----------------
__global__ __launch_bounds__(256) void k_count(const int* __restrict__ ei, int* __restrict__ counts)
{
    int e = blockIdx.x*256 + threadIdx.x;
    if (e >= EE) return;
    atomicAdd(&counts[ei[EE+e]], 1);
}

// ---------------- exclusive scan over counts -> rowptr (single block) ----------------
__global__ __launch_bounds__(1024) void k_scan(const int* __restrict__ counts, int* __restrict__ rowptr)
{
    __shared__ int sh[1024];
    const int CH = (NN + 1023)/1024;  // 49
    int t = threadIdx.x;
    int start = t*CH;
    int end = min(start+CH, NN);
    int s = 0;
    for (int i=start; i<end; i++) s += counts[i];
    sh[t] = s; __syncthreads();
    for (int off=1; off<1024; off<<=1){
        int v = (t>=off) ? sh[t-off] : 0;
        __syncthreads();
        sh[t] += v;
        __syncthreads();
    }
    int run = sh[t] - s;   // exclusive prefix
    for (int i=start; i<end; i++){ rowptr[i] = run; run += counts[i]; }
    if (t==1023) rowptr[NN] = run;
}

// ---------------- CSR fill: geometry + edge inputs in dst-sorted order ----------------
__global__ __launch_bounds__(256) void k_fill(
    const int* __restrict__ ei, const float* __restrict__ pos, const float* __restrict__ eattr,
    const int* __restrict__ rowptr, int* __restrict__ cursor,
    int* __restrict__ esrc, float* __restrict__ ein8)
{
    int e = blockIdx.x*256 + threadIdx.x;
    if (e >= EE) return;
    int src = ei[e], dst = ei[EE+e];
    float dx = pos[dst*3+0]-pos[src*3+0];
    float dy = pos[dst*3+1]-pos[src*3+1];
    float dz = pos[dst*3+2]-pos[src*3+2];
    float d = sqrtf(dx*dx+dy*dy+dz*dz+EPSF);
    float inv = 1.0f/d;
    int slot = rowptr[dst] + atomicAdd(&cursor[dst], 1);
    esrc[slot] = src;
    float4* p = (float4*)(ein8 + (size_t)slot*8);
    p[0] = make_float4(d, eattr[e*4+0], eattr[e*4+1], eattr[e*4+2]);
    p[1] = make_float4(eattr[e*4+3], dx*inv, dy*inv, dz*inv);
}

// ---------------- node embedding (fp32 master + packed bf16 quad gather copy) ----------------
// nbf layout: [n][f][4] = {s, v0, v1, v2} bf16 -> one aligned 8B load per (n,f)
__global__ __launch_bounds__(256) void k_embed(
    const float* __restrict__ x, const float* __restrict__ pos,
    const float* __restrict__ W_es, const float* __restrict__ b_es,
    const float* __restrict__ W_ev,
    float* __restrict__ ns, float* __restrict__ nv, __hip_bfloat16* __restrict__ nbf)
{
    int tid = blockIdx.x*256 + threadIdx.x;
    if (tid >= NN*FF) return;
    int n = tid >> 5, f = tid & 31;
    float x0=x[n*5+0], x1=x[n*5+1], x2=x[n*5+2], x3=x[n*5+3], x4=x[n*5+4];
    float s  = b_es[f] + x0*W_es[f] + x1*W_es[32+f] + x2*W_es[64+f] + x3*W_es[96+f] + x4*W_es[128+f];
    float vm =           x0*W_ev[f] + x1*W_ev[32+f] + x2*W_ev[64+f] + x3*W_ev[96+f] + x4*W_ev[128+f];
    float v0 = vm*pos[n*3+0], v1 = vm*pos[n*3+1], v2 = vm*pos[n*3+2];
    ns[tid] = s;
    nv[n*96+f*3+0] = v0;
    nv[n*96+f*3+1] = v1;
    nv[n*96+f*3+2] = v2;
    us4 q;
    q[0] = (unsigned short)f2bf_s(s);
    q[1] = (unsigned short)f2bf_s(v0);
    q[2] = (unsigned short)f2bf_s(v1);
    q[3] = (unsigned short)f2bf_s(v2);
    *(us4*)((unsigned short*)nbf + (size_t)n*128 + f*4) = q;
}

// ---------------- W2 transpose -> bf16: [l][k(64)][j(96)] -> [l][j(96)][k(64)] ----------------
__global__ __launch_bounds__(256) void k_transpose(const float* __restrict__ W2, __hip_bfloat16* __restrict__ W2bf)
{
    int tid = blockIdx.x*256 + threadIdx.x;
    if (tid >= NLAYERS*6144) return;
    int l = tid / 6144; int r = tid - l*6144;
    int j = r >> 6; int k = r & 63;
    W2bf[l*6144 + j*64 + k] = __float2bfloat16(W2[l*6144 + k*96 + j]);
}

// ---------------- W_inv transpose -> bf16: [k(64)][n(128)] -> [n(128)][k(64)] ----------------
__global__ __launch_bounds__(256) void k_transposeW(const float* __restrict__ W_inv, __hip_bfloat16* __restrict__ WinvT)
{
    int tid = blockIdx.x*256 + threadIdx.x;
    if (tid >= 8192) return;
    int n = tid >> 6, k = tid & 63;
    WinvT[n*64 + k] = __float2bfloat16(W_inv[k*128 + n]);
}

// ---------------- edge MLP via MFMA -> bf16 h rows [E][96] (edge-major) ----------------
__global__ __launch_bounds__(256) void k_mlp_mfma(
    const float* __restrict__ ein8,
    const float* __restrict__ W1l, const float* __restrict__ b1l,
    const __hip_bfloat16* __restrict__ W2bfl, const float* __restrict__ b2l,
    __hip_bfloat16* __restrict__ hbuf)
{
    __shared__ __hip_bfloat16 cstage[2][64][100];   // 2 x 12.8 KB
    const int tid  = threadIdx.x;
    const int lane = tid & 63;
    const int wave = tid >> 6;
    const int m    = lane & 15;
    const int quad = lane >> 4;

    for (int t=0; t<TILES; t++){
        const long long blockbase = ((long long)blockIdx.x*TILES + t) * 64;
        const long long edge = blockbase + wave*16 + m;

        const float4* p = (const float4*)(ein8 + edge*8);
        float4 q0 = p[0], q1 = p[1];
        float e0=q0.x, e1=q0.y, e2=q0.z, e3=q0.w, e4=q1.x;

        short8 afrag[2];
        #pragma unroll
        for (int s=0;s<2;s++){
            #pragma unroll
            for (int j=0;j<8;j++){
                int k = s*32 + quad*8 + j;
                float a = b1l[k] + e0*W1l[k] + e1*W1l[64+k] + e2*W1l[128+k]
                                 + e3*W1l[192+k] + e4*W1l[256+k];
                afrag[s][j] = f2bf_s(elu_f(a));
            }
        }

        f32x4 acc[6];
        #pragma unroll
        for (int u=0;u<6;u++) acc[u] = (f32x4){0.f,0.f,0.f,0.f};

        #pragma unroll
        for (int s=0;s<2;s++){
            #pragma unroll
            for (int u=0;u<6;u++){
                int n = u*16 + m;
                short8 bfrag = *(const short8*)(W2bfl + n*64 + s*32 + quad*8);
                acc[u] = __builtin_amdgcn_mfma_f32_16x16x32_bf16(afrag[s], bfrag, acc[u], 0, 0, 0);
            }
        }

        __hip_bfloat16 (*cs)[100] = cstage[t&1];
        #pragma unroll
        for (int u=0;u<6;u++){
            int n = u*16 + m;
            float bias = b2l[n];
            #pragma unroll
            for (int r=0;r<4;r++){
                cs[wave*16 + quad*4 + r][n] = __float2bfloat16(acc[u][r] + bias);
            }
        }
        __syncthreads();

        #pragma unroll
        for (int it=0; it<6; it++){
            int flat = it*256 + tid;
            int e = flat / 24, seg = flat % 24;
            float2 val = *(const float2*)&cs[e][seg*4];
            *(float2*)(hbuf + (blockbase + e)*96 + seg*4) = val;
        }
    }
}

// ---------------- CSR gather-aggregate + node update (no atomics) ----------------
// One 64-lane wave per node: halves h2=0/1 take alternating slots (serial depth
// deg/2), combined by one shfl_xor(32). Depth-1 pipeline within each half.
// nbf quad layout: one 8B load per (slot,f).
__global__ __launch_bounds__(256) void k_agg(
    const int* __restrict__ rowptr, const int* __restrict__ esrc,
    const float* __restrict__ ein8, const __hip_bfloat16* __restrict__ hbuf,
    float* __restrict__ ns, float* __restrict__ nv,
    const __hip_bfloat16* __restrict__ nbfi,
    const float* __restrict__ Wsl, const float* __restrict__ Wvl,
    __hip_bfloat16* __restrict__ nbfo)
{
    int tid = blockIdx.x*256 + threadIdx.x;
    int n = tid >> 6;
    if (n >= NN) return;
    int lane = threadIdx.x & 63;
    int f = lane & 31, h2 = lane >> 5;
    int beg = rowptr[n], end = rowptr[n+1];
    float as=0.f, a0=0.f, a1=0.f, a2=0.f;
    {
        const unsigned short* hb = (const unsigned short*)hbuf;
        const unsigned short* nb = (const unsigned short*)nbfi;
        int slot = beg + h2;
        if (slot < end){
            int src = esrc[slot];
            float4 u = *(const float4*)(ein8 + (size_t)slot*8 + 4);
            size_t ho = (size_t)slot*96;
            unsigned short hx=hb[ho+f], hy=hb[ho+32+f], hz=hb[ho+64+f];
            us4 nq = *(const us4*)(nb + (size_t)src*128 + f*4);
            while (true){
                int slot2 = slot + 2;
                float4 uN=u; unsigned short hxN=0,hyN=0,hzN=0; us4 nqN=nq;
                if (slot2 < end){
                    int srcN = esrc[slot2];
                    uN = *(const float4*)(ein8 + (size_t)slot2*8 + 4);
                    size_t ho2 = (size_t)slot2*96;
                    hxN=hb[ho2+f]; hyN=hb[ho2+32+f]; hzN=hb[ho2+64+f];
                    nqN = *(const us4*)(nb + (size_t)srcN*128 + f*4);
                }
                float gs=bf2f(hx), gv=bf2f(hy), gsv=bf2f(hz);
                float s  = bf2f(nq[0]);
                float v0 = bf2f(nq[1]), v1 = bf2f(nq[2]), v2 = bf2f(nq[3]);
                float c = gsv*s;
                as += gs*s;
                a0 += gv*v0 + c*u.y;
                a1 += gv*v1 + c*u.z;
                a2 += gv*v2 + c*u.w;
                if (slot2 >= end) break;
                slot = slot2; u=uN; hx=hxN; hy=hyN; hz=hzN; nq=nqN;
            }
        }
    }
    // combine the two halves
    as += __shfl_xor(as, 32);
    a0 += __shfl_xor(a0, 32);
    a1 += __shfl_xor(a1, 32);
    a2 += __shfl_xor(a2, 32);
    float invd = 1.f/fmaxf((float)(end-beg), 1.f);
    as*=invd; a0*=invd; a1*=invd; a2*=invd;
    float os=0.f, o0=0.f, o1=0.f, o2=0.f;
    #pragma unroll
    for (int k=0;k<FF;k++){
        float bs = __shfl(as, k, 32);
        float b0 = __shfl(a0, k, 32);
        float b1 = __shfl(a1, k, 32);
        float b2 = __shfl(a2, k, 32);
        float ws = Wsl[k*32+f];
        float wv = Wvl[k*32+f];
        os += bs*ws; o0 += b0*wv; o1 += b1*wv; o2 += b2*wv;
    }
    if (h2 == 0){
        float sn = ns[n*32+f] + elu_f(os);
        float w0 = nv[n*96+f*3+0] + o0;
        float w1 = nv[n*96+f*3+1] + o1;
        float w2 = nv[n*96+f*3+2] + o2;
        ns[n*32+f] = sn;
        nv[n*96+f*3+0] = w0;
        nv[n*96+f*3+1] = w1;
        nv[n*96+f*3+2] = w2;
        us4 q;
        q[0] = (unsigned short)f2bf_s(sn);
        q[1] = (unsigned short)f2bf_s(w0);
        q[2] = (unsigned short)f2bf_s(w1);
        q[3] = (unsigned short)f2bf_s(w2);
        *(us4*)((unsigned short*)nbfo + (size_t)n*128 + f*4) = q;
    }
}

// ---------------- graph boundaries via binary search (batch is sorted) ----------------
__global__ __launch_bounds__(256) void k_gbounds(const int* __restrict__ batch, int* __restrict__ gstart)
{
    int g = blockIdx.x*256 + threadIdx.x;
    if (g > GG) return;
    int lo = 0, hi = NN;
    while (lo < hi){
        int mid = (lo+hi) >> 1;
        if (batch[mid] < g) lo = mid+1; else hi = mid;
    }
    gstart[g] = lo;
}

// ---------------- invariant map via MFMA: inv[N,128] = feat[N,64] @ W_inv (no bias) ----------------
// Wave handles 16 nodes; A-frags built directly from ns/nv (feat = [s | ||v||]).
__global__ __launch_bounds__(256) void k_invgemm(
    const float* __restrict__ ns, const float* __restrict__ nv,
    const __hip_bfloat16* __restrict__ WinvT,   // [128][64] bf16
    float* __restrict__ inv)                    // [N][128] fp32
{
    const int tid  = threadIdx.x;
    const int lane = tid & 63;
    const int wave = tid >> 6;
    const int m    = lane & 15;
    const int quad = lane >> 4;
    const int tilebase = blockIdx.x*64 + wave*16;
    const int node = tilebase + m;
    const bool valid = node < NN;

    short8 afrag[2];
    #pragma unroll
    for (int j=0;j<8;j++){
        int k = quad*8 + j;            // 0..31
        float fs = valid ? ns[(size_t)node*32 + k] : 0.f;
        afrag[0][j] = f2bf_s(fs);
        float v0 = valid ? nv[(size_t)node*96 + k*3+0] : 0.f;
        float v1 = valid ? nv[(size_t)node*96 + k*3+1] : 0.f;
        float v2 = valid ? nv[(size_t)node*96 + k*3+2] : 0.f;
        afrag[1][j] = f2bf_s(sqrtf(v0*v0+v1*v1+v2*v2+EPSF));
    }
    f32x4 acc[8];
    #pragma unroll
    for (int t=0;t<8;t++) acc[t] = (f32x4){0.f,0.f,0.f,0.f};
    #pragma unroll
    for (int s=0;s<2;s++){
        #pragma unroll
        for (int t=0;t<8;t++){
            short8 bfrag = *(const short8*)(WinvT + (t*16+m)*64 + s*32 + quad*8);
            acc[t] = __builtin_amdgcn_mfma_f32_16x16x32_bf16(afrag[s], bfrag, acc[t], 0, 0, 0);
        }
    }
    #pragma unroll
    for (int r=0;r<4;r++){
        int nrow = tilebase + quad*4 + r;
        if (nrow < NN){
            #pragma unroll
            for (int t=0;t<8;t++){
                inv[(size_t)nrow*128 + t*16 + m] = acc[t][r];
            }
        }
    }
}

// ---------------- graph mean pool over inv (coalesced, no LDS/sync) ----------------
__global__ __launch_bounds__(128) void k_pool(
    const int* __restrict__ gstart, const float* __restrict__ inv,
    const float* __restrict__ b_inv, float* __restrict__ xg)
{
    int g = blockIdx.x, j = threadIdx.x;
    int beg = gstart[g], end = gstart[g+1];
    float acc = 0.f;
    for (int n=beg; n<end; n++) acc += inv[(size_t)n*128 + j];
    int cnt = end - beg;
    float cp = fmaxf((float)cnt, 1.f);
    xg[g*128+j] = acc/cp + b_inv[j]*((float)cnt/cp);
}

// ---------------- per-column mean/rstd over G rows ----------------
__global__ __launch_bounds__(256) void k_colstats(
    const float* __restrict__ in, float* __restrict__ mean, float* __restrict__ rstd)
{
    int j = blockIdx.x;
    float s=0.f, q=0.f;
    for (int g=threadIdx.x; g<GG; g+=256){
        float x = in[g*128+j];
        s += x; q += x*x;
    }
    __shared__ float rs[256], rq[256];
    rs[threadIdx.x]=s; rq[threadIdx.x]=q;
    __syncthreads();
    for (int st=128; st>0; st>>=1){
        if (threadIdx.x < st){ rs[threadIdx.x]+=rs[threadIdx.x+st]; rq[threadIdx.x]+=rq[threadIdx.x+st]; }
        __syncthreads();
    }
    if (threadIdx.x==0){
        float m = rs[0]/(float)GG;
        float v = rq[0]/(float)GG - m*m;
        mean[j]=m; rstd[j]=rsqrtf(v+1e-5f);
    }
}

// ---------------- BN1 + ELU + FC1 ----------------
__global__ __launch_bounds__(128) void k_fc1(
    const float* __restrict__ xg, const float* __restrict__ mean, const float* __restrict__ rstd,
    const float* __restrict__ g1, const float* __restrict__ be1,
    const float* __restrict__ Wf1, const float* __restrict__ bf1,
    float* __restrict__ z1)
{
    int g = blockIdx.x, j = threadIdx.x;
    __shared__ float a[128];
    float xin = xg[g*128+j];
    a[j] = elu_f((xin-mean[j])*rstd[j]*g1[j]+be1[j]);
    __syncthreads();
    float z = bf1[j];
    #pragma unroll 8
    for (int k=0;k<128;k++) z += a[k]*Wf1[k*128+j];
    z1[g*128+j] = z;
}

// ---------------- BN2 + ELU + FC2 -> out ----------------
__global__ __launch_bounds__(128) void k_out(
    const float* __restrict__ z1, const float* __restrict__ mean, const float* __restrict__ rstd,
    const float* __restrict__ g2, const float* __restrict__ be2,
    const float* __restrict__ Wf2, const float* __restrict__ bf2,
    float* __restrict__ out)
{
    int g = blockIdx.x, j = threadIdx.x;
    float a = elu_f((z1[g*128+j]-mean[j])*rstd[j]*g2[j]+be2[j]) * Wf2[j];
    __shared__ float red[128];
    red[j]=a; __syncthreads();
    for (int st=64; st>0; st>>=1){
        if (j<st) red[j]+=red[j+st];
        __syncthreads();
    }
    if (j==0) out[g] = red[0] + bf2[0];
}

extern "C" void kernel_launch(void* const* d_in, const int* in_sizes, int n_in,
                              void* d_out, int out_size, void* d_ws, size_t ws_size,
                              hipStream_t stream)
{
    const float* x      = (const float*)d_in[0];
    const float* pos    = (const float*)d_in[1];
    const int*   ei     = (const int*)d_in[2];
    const float* eattr  = (const float*)d_in[3];
    const int*   batch  = (const int*)d_in[4];
    const float* W_es   = (const float*)d_in[5];
    const float* b_es   = (const float*)d_in[6];
    const float* W_ev   = (const float*)d_in[7];
    const float* W1     = (const float*)d_in[8];
    const float* b1     = (const float*)d_in[9];
    const float* W2     = (const float*)d_in[10];
    const float* b2     = (const float*)d_in[11];
    const float* Ws     = (const float*)d_in[12];
    const float* Wv     = (const float*)d_in[13];
    const float* W_inv  = (const float*)d_in[14];
    const float* b_inv  = (const float*)d_in[15];
    const float* g1     = (const float*)d_in[16];
    const float* be1    = (const float*)d_in[17];
    const float* Wf1    = (const float*)d_in[18];
    const float* bf1    = (const float*)d_in[19];
    const float* g2     = (const float*)d_in[20];
    const float* be2    = (const float*)d_in[21];
    const float* Wf2    = (const float*)d_in[22];
    const float* bf2    = (const float*)d_in[23];
    float* out = (float*)d_out;

    // ---- workspace layout (4-byte units, 64B aligned blocks) ----
    // Total ~236.4 MB (< ~256 MiB ws_size; R7 lesson). inv[N][128] fp32
    // (25.6 MB) ALIASES hbuf — hbuf is dead after the last k_agg.
    char* base = (char*)d_ws;
    size_t off = 0;
    auto alloc = [&](size_t elems4) { // elems in 4-byte units
        void* p = base + off;
        off += ((elems4*4 + 63) & ~size_t(63));
        return p;
    };
    int*   counts = (int*)  alloc(50000);       // zeroed
    int*   cursor = (int*)  alloc(50000);       // zeroed
    size_t zero_bytes = off;
    int*   rowptr = (int*)  alloc(50001);
    int*   esrc   = (int*)  alloc(800000);
    float* ein8   = (float*)alloc(6400000);     // [E][8]: d,a0..a3 | a3,u0,u1,u2
    float* ns     = (float*)alloc(1600000);     // fp32 master, in-place residual
    float* nv     = (float*)alloc(4800000);
    __hip_bfloat16* nbfA = (__hip_bfloat16*)alloc(3200000); // [N][32][4] bf16 quads = 12.8 MB
    __hip_bfloat16* nbfB = (__hip_bfloat16*)alloc(3200000);
    __hip_bfloat16* W2bf = (__hip_bfloat16*)alloc(12288);   // NL*96*64 bf16
    __hip_bfloat16* WinvT= (__hip_bfloat16*)alloc(4096);    // [128][64] bf16
    int*   gstart = (int*)  alloc(2049);
    float* xg     = (float*)alloc(262144);
    float* z1     = (float*)alloc(262144);
    float* m1     = (float*)alloc(128);
    float* r1     = (float*)alloc(128);
    float* m2     = (float*)alloc(128);
    float* r2     = (float*)alloc(128);
    __hip_bfloat16* hbuf = (__hip_bfloat16*)alloc(38400000); // [E][96] bf16 edge-major
    float* inv    = (float*)hbuf;               // alias: used only after layers

    hipMemsetAsync(d_ws, 0, zero_bytes, stream);

    // ---- setup: CSR build + embedding + weight transposes ----
    k_count    <<<EE/256, 256, 0, stream>>>(ei, counts);
    k_scan     <<<1, 1024, 0, stream>>>(counts, rowptr);
    k_fill     <<<EE/256, 256, 0, stream>>>(ei, pos, eattr, rowptr, cursor, esrc, ein8);
    k_embed    <<<NN*FF/256, 256, 0, stream>>>(x, pos, W_es, b_es, W_ev, ns, nv, nbfA);
    k_transpose<<<(NLAYERS*6144+255)/256, 256, 0, stream>>>(W2, W2bf);
    k_transposeW<<<(8192+255)/256, 256, 0, stream>>>(W_inv, WinvT);

    // ---- message-passing layers (bf16 gather copy double-buffered) ----
    for (int l=0; l<NLAYERS; l++){
        const __hip_bfloat16* nbfi = (l&1) ? nbfB : nbfA;
        __hip_bfloat16* nbfo = (l&1) ? nbfA : nbfB;
        k_mlp_mfma<<<EE/(64*TILES), 256, 0, stream>>>(ein8,
            W1 + l*320, b1 + l*64, W2bf + l*6144, b2 + l*96, hbuf);
        k_agg<<<(NN*64+255)/256, 256, 0, stream>>>(rowptr, esrc, ein8, hbuf,
            ns, nv, nbfi, Ws + l*1024, Wv + l*1024, nbfo);
    }
    // fp32 ns/nv hold final node features (in-place updates)

    // ---- invariant map (MFMA) + pooling + head ----
    k_gbounds <<<(GG+1+255)/256, 256, 0, stream>>>(batch, gstart);
    k_invgemm <<<(NN+63)/64, 256, 0, stream>>>(ns, nv, WinvT, inv);
    k_pool    <<<GG, 128, 0, stream>>>(gstart, inv, b_inv, xg);
    k_colstats<<<128, 256, 0, stream>>>(xg, m1, r1);
    k_fc1     <<<GG, 128, 0, stream>>>(xg, m1, r1, g1, be1, Wf1, bf1, z1);
    k_colstats<<<128, 256, 0, stream>>>(z1, m2, r2);
    k_out     <<<GG, 128, 0, stream>>>(z1, m2, r2, g2, be2, Wf2, bf2, out);
}

// Round 11
// 930.270 us; speedup vs baseline: 1.3445x; 1.3445x over previous
//
#include <hip/hip_runtime.h>
#include <hip/hip_bf16.h>
#include <math.h>

#define NN 50000
#define EE 800000
#define FF 32
#define HH 64
#define GG 2048
#define NLAYERS 4
#define EPSF 1e-6f
#define TILES 4

typedef __attribute__((ext_vector_type(8))) short short8;
typedef __attribute__((ext_vector_type(4))) float f32x4;
typedef __attribute__((ext_vector_type(4))) unsigned short us4;

__device__ __forceinline__ float elu_f(float x){ return x > 0.0f ? x : __expf(x) - 1.0f; }
__device__ __forceinline__ short f2bf_s(float x){
    __hip_bfloat16 h = __float2bfloat16(x);
    return *reinterpret_cast<short*>(&h);
}
__device__ __forceinline__ float bf2f(unsigned short u){
    unsigned int w = ((unsigned int)u) << 16;
    return *reinterpret_cast<float*>(&w);
}

// ---------------- in-degree count ----------------
__global__ __launch_bounds__(256) void k_count(const int* __restrict__ ei, int* __restrict__ counts)
{
    int e = blockIdx.x*256 + threadIdx.x;
    if (e >= EE) return;
    atomicAdd(&counts[ei[EE+e]], 1);
}

// ---------------- exclusive scan over counts -> rowptr (single block) ----------------
__global__ __launch_bounds__(1024) void k_scan(const int* __restrict__ counts, int* __restrict__ rowptr)
{
    __shared__ int sh[1024];
    const int CH = (NN + 1023)/1024;  // 49
    int t = threadIdx.x;
    int start = t*CH;
    int end = min(start+CH, NN);
    int s = 0;
    for (int i=start; i<end; i++) s += counts[i];
    sh[t] = s; __syncthreads();
    for (int off=1; off<1024; off<<=1){
        int v = (t>=off) ? sh[t-off] : 0;
        __syncthreads();
        sh[t] += v;
        __syncthreads();
    }
    int run = sh[t] - s;   // exclusive prefix
    for (int i=start; i<end; i++){ rowptr[i] = run; run += counts[i]; }
    if (t==1023) rowptr[NN] = run;
}

// ---------------- CSR fill: geometry + edge inputs in dst-sorted order ----------------
__global__ __launch_bounds__(256) void k_fill(
    const int* __restrict__ ei, const float* __restrict__ pos, const float* __restrict__ eattr,
    const int* __restrict__ rowptr, int* __restrict__ cursor,
    int* __restrict__ esrc, float* __restrict__ ein8)
{
    int e = blockIdx.x*256 + threadIdx.x;
    if (e >= EE) return;
    int src = ei[e], dst = ei[EE+e];
    float dx = pos[dst*3+0]-pos[src*3+0];
    float dy = pos[dst*3+1]-pos[src*3+1];
    float dz = pos[dst*3+2]-pos[src*3+2];
    float d = sqrtf(dx*dx+dy*dy+dz*dz+EPSF);
    float inv = 1.0f/d;
    int slot = rowptr[dst] + atomicAdd(&cursor[dst], 1);
    esrc[slot] = src;
    float4* p = (float4*)(ein8 + (size_t)slot*8);
    p[0] = make_float4(d, eattr[e*4+0], eattr[e*4+1], eattr[e*4+2]);
    p[1] = make_float4(eattr[e*4+3], dx*inv, dy*inv, dz*inv);
}

// ---------------- node embedding (fp32 master + packed bf16 quad gather copy) ----------------
// nbf layout: [n][f][4] = {s, v0, v1, v2} bf16 -> one aligned 8B load per (n,f)
__global__ __launch_bounds__(256) void k_embed(
    const float* __restrict__ x, const float* __restrict__ pos,
    const float* __restrict__ W_es, const float* __restrict__ b_es,
    const float* __restrict__ W_ev,
    float* __restrict__ ns, float* __restrict__ nv, __hip_bfloat16* __restrict__ nbf)
{
    int tid = blockIdx.x*256 + threadIdx.x;
    if (tid >= NN*FF) return;
    int n = tid >> 5, f = tid & 31;
    float x0=x[n*5+0], x1=x[n*5+1], x2=x[n*5+2], x3=x[n*5+3], x4=x[n*5+4];
    float s  = b_es[f] + x0*W_es[f] + x1*W_es[32+f] + x2*W_es[64+f] + x3*W_es[96+f] + x4*W_es[128+f];
    float vm =           x0*W_ev[f] + x1*W_ev[32+f] + x2*W_ev[64+f] + x3*W_ev[96+f] + x4*W_ev[128+f];
    float v0 = vm*pos[n*3+0], v1 = vm*pos[n*3+1], v2 = vm*pos[n*3+2];
    ns[tid] = s;
    nv[n*96+f*3+0] = v0;
    nv[n*96+f*3+1] = v1;
    nv[n*96+f*3+2] = v2;
    us4 q;
    q[0] = (unsigned short)f2bf_s(s);
    q[1] = (unsigned short)f2bf_s(v0);
    q[2] = (unsigned short)f2bf_s(v1);
    q[3] = (unsigned short)f2bf_s(v2);
    *(us4*)((unsigned short*)nbf + (size_t)n*128 + f*4) = q;
}

// ---------------- W2 transpose -> bf16: [l][k(64)][j(96)] -> [l][j(96)][k(64)] ----------------
__global__ __launch_bounds__(256) void k_transpose(const float* __restrict__ W2, __hip_bfloat16* __restrict__ W2bf)
{
    int tid = blockIdx.x*256 + threadIdx.x;
    if (tid >= NLAYERS*6144) return;
    int l = tid / 6144; int r = tid - l*6144;
    int j = r >> 6; int k = r & 63;
    W2bf[l*6144 + j*64 + k] = __float2bfloat16(W2[l*6144 + k*96 + j]);
}

// ---------------- W_inv transpose -> bf16: [k(64)][n(128)] -> [n(128)][k(64)] ----------------
__global__ __launch_bounds__(256) void k_transposeW(const float* __restrict__ W_inv, __hip_bfloat16* __restrict__ WinvT)
{
    int tid = blockIdx.x*256 + threadIdx.x;
    if (tid >= 8192) return;
    int n = tid >> 6, k = tid & 63;
    WinvT[n*64 + k] = __float2bfloat16(W_inv[k*128 + n]);
}

// ---------------- edge MLP via MFMA -> bf16 h rows [E][96] (edge-major) ----------------
__global__ __launch_bounds__(256) void k_mlp_mfma(
    const float* __restrict__ ein8,
    const float* __restrict__ W1l, const float* __restrict__ b1l,
    const __hip_bfloat16* __restrict__ W2bfl, const float* __restrict__ b2l,
    __hip_bfloat16* __restrict__ hbuf)
{
    __shared__ __hip_bfloat16 cstage[2][64][100];   // 2 x 12.8 KB
    const int tid  = threadIdx.x;
    const int lane = tid & 63;
    const int wave = tid >> 6;
    const int m    = lane & 15;
    const int quad = lane >> 4;

    for (int t=0; t<TILES; t++){
        const long long blockbase = ((long long)blockIdx.x*TILES + t) * 64;
        const long long edge = blockbase + wave*16 + m;

        const float4* p = (const float4*)(ein8 + edge*8);
        float4 q0 = p[0], q1 = p[1];
        float e0=q0.x, e1=q0.y, e2=q0.z, e3=q0.w, e4=q1.x;

        short8 afrag[2];
        #pragma unroll
        for (int s=0;s<2;s++){
            #pragma unroll
            for (int j=0;j<8;j++){
                int k = s*32 + quad*8 + j;
                float a = b1l[k] + e0*W1l[k] + e1*W1l[64+k] + e2*W1l[128+k]
                                 + e3*W1l[192+k] + e4*W1l[256+k];
                afrag[s][j] = f2bf_s(elu_f(a));
            }
        }

        f32x4 acc[6];
        #pragma unroll
        for (int u=0;u<6;u++) acc[u] = (f32x4){0.f,0.f,0.f,0.f};

        #pragma unroll
        for (int s=0;s<2;s++){
            #pragma unroll
            for (int u=0;u<6;u++){
                int n = u*16 + m;
                short8 bfrag = *(const short8*)(W2bfl + n*64 + s*32 + quad*8);
                acc[u] = __builtin_amdgcn_mfma_f32_16x16x32_bf16(afrag[s], bfrag, acc[u], 0, 0, 0);
            }
        }

        __hip_bfloat16 (*cs)[100] = cstage[t&1];
        #pragma unroll
        for (int u=0;u<6;u++){
            int n = u*16 + m;
            float bias = b2l[n];
            #pragma unroll
            for (int r=0;r<4;r++){
                cs[wave*16 + quad*4 + r][n] = __float2bfloat16(acc[u][r] + bias);
            }
        }
        __syncthreads();

        #pragma unroll
        for (int it=0; it<6; it++){
            int flat = it*256 + tid;
            int e = flat / 24, seg = flat % 24;
            float2 val = *(const float2*)&cs[e][seg*4];
            *(float2*)(hbuf + (blockbase + e)*96 + seg*4) = val;
        }
    }
}

// ---------------- CSR gather-aggregate + node update (no atomics) ----------------
// R9 mapping restored: 32 lanes per node (2 nodes/wave), depth-1 pipeline.
// (R10 post-mortem: wave-per-node variant -> VGPR 28->80, occupancy 65->28%,
//  94.6->167 µs. TLP beats serial-depth halving for this latency-bound gather.)
// Quad nbf layout kept: one 8B load per (slot,f) instead of 4 scalars.
__global__ __launch_bounds__(256) void k_agg(
    const int* __restrict__ rowptr, const int* __restrict__ esrc,
    const float* __restrict__ ein8, const __hip_bfloat16* __restrict__ hbuf,
    float* __restrict__ ns, float* __restrict__ nv,
    const __hip_bfloat16* __restrict__ nbfi,
    const float* __restrict__ Wsl, const float* __restrict__ Wvl,
    __hip_bfloat16* __restrict__ nbfo)
{
    int tid = blockIdx.x*256 + threadIdx.x;
    int n = tid >> 5, f = tid & 31;
    if (n >= NN) return;
    int beg = rowptr[n], end = rowptr[n+1];
    float as=0.f, a0=0.f, a1=0.f, a2=0.f;
    if (beg < end){
        const unsigned short* hb = (const unsigned short*)hbuf;
        const unsigned short* nb = (const unsigned short*)nbfi;
        // stage slot = beg
        int src = esrc[beg];
        float4 u = *(const float4*)(ein8 + (size_t)beg*8 + 4);
        size_t hoff = (size_t)beg*96;
        unsigned short hx = hb[hoff+f], hy = hb[hoff+32+f], hz = hb[hoff+64+f];
        us4 nq = *(const us4*)(nb + (size_t)src*128 + f*4);
        for (int slot=beg; slot<end; slot++){
            float4 uN=u; unsigned short hxN=0,hyN=0,hzN=0; us4 nqN=nq;
            if (slot+1 < end){
                int srcN = esrc[slot+1];
                uN = *(const float4*)(ein8 + (size_t)(slot+1)*8 + 4);
                size_t ho = (size_t)(slot+1)*96;
                hxN = hb[ho+f]; hyN = hb[ho+32+f]; hzN = hb[ho+64+f];
                nqN = *(const us4*)(nb + (size_t)srcN*128 + f*4);
            }
            float gs = bf2f(hx), gv = bf2f(hy), gsv = bf2f(hz);
            float s  = bf2f(nq[0]);
            float v0 = bf2f(nq[1]), v1 = bf2f(nq[2]), v2 = bf2f(nq[3]);
            float c = gsv*s;
            as += gs*s;
            a0 += gv*v0 + c*u.y;
            a1 += gv*v1 + c*u.z;
            a2 += gv*v2 + c*u.w;
            u=uN; hx=hxN; hy=hyN; hz=hzN; nq=nqN;
        }
    }
    float invd = 1.f/fmaxf((float)(end-beg), 1.f);
    as*=invd; a0*=invd; a1*=invd; a2*=invd;
    float os=0.f, o0=0.f, o1=0.f, o2=0.f;
    #pragma unroll
    for (int k=0;k<FF;k++){
        float bs = __shfl(as, k, 32);
        float b0 = __shfl(a0, k, 32);
        float b1 = __shfl(a1, k, 32);
        float b2 = __shfl(a2, k, 32);
        float ws = Wsl[k*32+f];
        float wv = Wvl[k*32+f];
        os += bs*ws; o0 += b0*wv; o1 += b1*wv; o2 += b2*wv;
    }
    float sn = ns[n*32+f] + elu_f(os);
    float w0 = nv[n*96+f*3+0] + o0;
    float w1 = nv[n*96+f*3+1] + o1;
    float w2 = nv[n*96+f*3+2] + o2;
    ns[n*32+f] = sn;
    nv[n*96+f*3+0] = w0;
    nv[n*96+f*3+1] = w1;
    nv[n*96+f*3+2] = w2;
    us4 q;
    q[0] = (unsigned short)f2bf_s(sn);
    q[1] = (unsigned short)f2bf_s(w0);
    q[2] = (unsigned short)f2bf_s(w1);
    q[3] = (unsigned short)f2bf_s(w2);
    *(us4*)((unsigned short*)nbfo + (size_t)n*128 + f*4) = q;
}

// ---------------- graph boundaries via binary search (batch is sorted) ----------------
__global__ __launch_bounds__(256) void k_gbounds(const int* __restrict__ batch, int* __restrict__ gstart)
{
    int g = blockIdx.x*256 + threadIdx.x;
    if (g > GG) return;
    int lo = 0, hi = NN;
    while (lo < hi){
        int mid = (lo+hi) >> 1;
        if (batch[mid] < g) lo = mid+1; else hi = mid;
    }
    gstart[g] = lo;
}

// ---------------- invariant map via MFMA: inv[N,128] = feat[N,64] @ W_inv (no bias) ----------------
__global__ __launch_bounds__(256) void k_invgemm(
    const float* __restrict__ ns, const float* __restrict__ nv,
    const __hip_bfloat16* __restrict__ WinvT,   // [128][64] bf16
    float* __restrict__ inv)                    // [N][128] fp32
{
    const int tid  = threadIdx.x;
    const int lane = tid & 63;
    const int wave = tid >> 6;
    const int m    = lane & 15;
    const int quad = lane >> 4;
    const int tilebase = blockIdx.x*64 + wave*16;
    const int node = tilebase + m;
    const bool valid = node < NN;

    short8 afrag[2];
    #pragma unroll
    for (int j=0;j<8;j++){
        int k = quad*8 + j;            // 0..31
        float fs = valid ? ns[(size_t)node*32 + k] : 0.f;
        afrag[0][j] = f2bf_s(fs);
        float v0 = valid ? nv[(size_t)node*96 + k*3+0] : 0.f;
        float v1 = valid ? nv[(size_t)node*96 + k*3+1] : 0.f;
        float v2 = valid ? nv[(size_t)node*96 + k*3+2] : 0.f;
        afrag[1][j] = f2bf_s(sqrtf(v0*v0+v1*v1+v2*v2+EPSF));
    }
    f32x4 acc[8];
    #pragma unroll
    for (int t=0;t<8;t++) acc[t] = (f32x4){0.f,0.f,0.f,0.f};
    #pragma unroll
    for (int s=0;s<2;s++){
        #pragma unroll
        for (int t=0;t<8;t++){
            short8 bfrag = *(const short8*)(WinvT + (t*16+m)*64 + s*32 + quad*8);
            acc[t] = __builtin_amdgcn_mfma_f32_16x16x32_bf16(afrag[s], bfrag, acc[t], 0, 0, 0);
        }
    }
    #pragma unroll
    for (int r=0;r<4;r++){
        int nrow = tilebase + quad*4 + r;
        if (nrow < NN){
            #pragma unroll
            for (int t=0;t<8;t++){
                inv[(size_t)nrow*128 + t*16 + m] = acc[t][r];
            }
        }
    }
}

// ---------------- graph mean pool over inv (coalesced, no LDS/sync) ----------------
__global__ __launch_bounds__(128) void k_pool(
    const int* __restrict__ gstart, const float* __restrict__ inv,
    const float* __restrict__ b_inv, float* __restrict__ xg)
{
    int g = blockIdx.x, j = threadIdx.x;
    int beg = gstart[g], end = gstart[g+1];
    float acc = 0.f;
    for (int n=beg; n<end; n++) acc += inv[(size_t)n*128 + j];
    int cnt = end - beg;
    float cp = fmaxf((float)cnt, 1.f);
    xg[g*128+j] = acc/cp + b_inv[j]*((float)cnt/cp);
}

// ---------------- per-column mean/rstd over G rows ----------------
__global__ __launch_bounds__(256) void k_colstats(
    const float* __restrict__ in, float* __restrict__ mean, float* __restrict__ rstd)
{
    int j = blockIdx.x;
    float s=0.f, q=0.f;
    for (int g=threadIdx.x; g<GG; g+=256){
        float x = in[g*128+j];
        s += x; q += x*x;
    }
    __shared__ float rs[256], rq[256];
    rs[threadIdx.x]=s; rq[threadIdx.x]=q;
    __syncthreads();
    for (int st=128; st>0; st>>=1){
        if (threadIdx.x < st){ rs[threadIdx.x]+=rs[threadIdx.x+st]; rq[threadIdx.x]+=rq[threadIdx.x+st]; }
        __syncthreads();
    }
    if (threadIdx.x==0){
        float m = rs[0]/(float)GG;
        float v = rq[0]/(float)GG - m*m;
        mean[j]=m; rstd[j]=rsqrtf(v+1e-5f);
    }
}

// ---------------- BN1 + ELU + FC1 ----------------
__global__ __launch_bounds__(128) void k_fc1(
    const float* __restrict__ xg, const float* __restrict__ mean, const float* __restrict__ rstd,
    const float* __restrict__ g1, const float* __restrict__ be1,
    const float* __restrict__ Wf1, const float* __restrict__ bf1,
    float* __restrict__ z1)
{
    int g = blockIdx.x, j = threadIdx.x;
    __shared__ float a[128];
    float xin = xg[g*128+j];
    a[j] = elu_f((xin-mean[j])*rstd[j]*g1[j]+be1[j]);
    __syncthreads();
    float z = bf1[j];
    #pragma unroll 8
    for (int k=0;k<128;k++) z += a[k]*Wf1[k*128+j];
    z1[g*128+j] = z;
}

// ---------------- BN2 + ELU + FC2 -> out ----------------
__global__ __launch_bounds__(128) void k_out(
    const float* __restrict__ z1, const float* __restrict__ mean, const float* __restrict__ rstd,
    const float* __restrict__ g2, const float* __restrict__ be2,
    const float* __restrict__ Wf2, const float* __restrict__ bf2,
    float* __restrict__ out)
{
    int g = blockIdx.x, j = threadIdx.x;
    float a = elu_f((z1[g*128+j]-mean[j])*rstd[j]*g2[j]+be2[j]) * Wf2[j];
    __shared__ float red[128];
    red[j]=a; __syncthreads();
    for (int st=64; st>0; st>>=1){
        if (j<st) red[j]+=red[j+st];
        __syncthreads();
    }
    if (j==0) out[g] = red[0] + bf2[0];
}

extern "C" void kernel_launch(void* const* d_in, const int* in_sizes, int n_in,
                              void* d_out, int out_size, void* d_ws, size_t ws_size,
                              hipStream_t stream)
{
    const float* x      = (const float*)d_in[0];
    const float* pos    = (const float*)d_in[1];
    const int*   ei     = (const int*)d_in[2];
    const float* eattr  = (const float*)d_in[3];
    const int*   batch  = (const int*)d_in[4];
    const float* W_es   = (const float*)d_in[5];
    const float* b_es   = (const float*)d_in[6];
    const float* W_ev   = (const float*)d_in[7];
    const float* W1     = (const float*)d_in[8];
    const float* b1     = (const float*)d_in[9];
    const float* W2     = (const float*)d_in[10];
    const float* b2     = (const float*)d_in[11];
    const float* Ws     = (const float*)d_in[12];
    const float* Wv     = (const float*)d_in[13];
    const float* W_inv  = (const float*)d_in[14];
    const float* b_inv  = (const float*)d_in[15];
    const float* g1     = (const float*)d_in[16];
    const float* be1    = (const float*)d_in[17];
    const float* Wf1    = (const float*)d_in[18];
    const float* bf1    = (const float*)d_in[19];
    const float* g2     = (const float*)d_in[20];
    const float* be2    = (const float*)d_in[21];
    const float* Wf2    = (const float*)d_in[22];
    const float* bf2    = (const float*)d_in[23];
    float* out = (float*)d_out;

    // ---- workspace layout (4-byte units, 64B aligned blocks) ----
    // Total ~236.4 MB (< ~256 MiB ws_size; R7 lesson). inv[N][128] fp32
    // (25.6 MB) ALIASES hbuf — hbuf is dead after the last k_agg.
    char* base = (char*)d_ws;
    size_t off = 0;
    auto alloc = [&](size_t elems4) { // elems in 4-byte units
        void* p = base + off;
        off += ((elems4*4 + 63) & ~size_t(63));
        return p;
    };
    int*   counts = (int*)  alloc(50000);       // zeroed
    int*   cursor = (int*)  alloc(50000);       // zeroed
    size_t zero_bytes = off;
    int*   rowptr = (int*)  alloc(50001);
    int*   esrc   = (int*)  alloc(800000);
    float* ein8   = (float*)alloc(6400000);     // [E][8]: d,a0..a3 | a3,u0,u1,u2
    float* ns     = (float*)alloc(1600000);     // fp32 master, in-place residual
    float* nv     = (float*)alloc(4800000);
    __hip_bfloat16* nbfA = (__hip_bfloat16*)alloc(3200000); // [N][32][4] bf16 quads = 12.8 MB
    __hip_bfloat16* nbfB = (__hip_bfloat16*)alloc(3200000);
    __hip_bfloat16* W2bf = (__hip_bfloat16*)alloc(12288);   // NL*96*64 bf16
    __hip_bfloat16* WinvT= (__hip_bfloat16*)alloc(4096);    // [128][64] bf16
    int*   gstart = (int*)  alloc(2049);
    float* xg     = (float*)alloc(262144);
    float* z1     = (float*)alloc(262144);
    float* m1     = (float*)alloc(128);
    float* r1     = (float*)alloc(128);
    float* m2     = (float*)alloc(128);
    float* r2     = (float*)alloc(128);
    __hip_bfloat16* hbuf = (__hip_bfloat16*)alloc(38400000); // [E][96] bf16 edge-major
    float* inv    = (float*)hbuf;               // alias: used only after layers

    hipMemsetAsync(d_ws, 0, zero_bytes, stream);

    // ---- setup: CSR build + embedding + weight transposes ----
    k_count    <<<EE/256, 256, 0, stream>>>(ei, counts);
    k_scan     <<<1, 1024, 0, stream>>>(counts, rowptr);
    k_fill     <<<EE/256, 256, 0, stream>>>(ei, pos, eattr, rowptr, cursor, esrc, ein8);
    k_embed    <<<NN*FF/256, 256, 0, stream>>>(x, pos, W_es, b_es, W_ev, ns, nv, nbfA);
    k_transpose<<<(NLAYERS*6144+255)/256, 256, 0, stream>>>(W2, W2bf);
    k_transposeW<<<(8192+255)/256, 256, 0, stream>>>(W_inv, WinvT);

    // ---- message-passing layers (bf16 gather copy double-buffered) ----
    for (int l=0; l<NLAYERS; l++){
        const __hip_bfloat16* nbfi = (l&1) ? nbfB : nbfA;
        __hip_bfloat16* nbfo = (l&1) ? nbfA : nbfB;
        k_mlp_mfma<<<EE/(64*TILES), 256, 0, stream>>>(ein8,
            W1 + l*320, b1 + l*64, W2bf + l*6144, b2 + l*96, hbuf);
        k_agg<<<(NN*32+255)/256, 256, 0, stream>>>(rowptr, esrc, ein8, hbuf,
            ns, nv, nbfi, Ws + l*1024, Wv + l*1024, nbfo);
    }
    // fp32 ns/nv hold final node features (in-place updates)

    // ---- invariant map (MFMA) + pooling + head ----
    k_gbounds <<<(GG+1+255)/256, 256, 0, stream>>>(batch, gstart);
    k_invgemm <<<(NN+63)/64, 256, 0, stream>>>(ns, nv, WinvT, inv);
    k_pool    <<<GG, 128, 0, stream>>>(gstart, inv, b_inv, xg);
    k_colstats<<<128, 256, 0, stream>>>(xg, m1, r1);
    k_fc1     <<<GG, 128, 0, stream>>>(xg, m1, r1, g1, be1, Wf1, bf1, z1);
    k_colstats<<<128, 256, 0, stream>>>(z1, m2, r2);
    k_out     <<<GG, 128, 0, stream>>>(z1, m2, r2, g2, be2, Wf2, bf2, out);
}

// Round 12
// 912.013 us; speedup vs baseline: 1.3714x; 1.0200x over previous
//
#include <hip/hip_runtime.h>
#include <hip/hip_bf16.h>
#include <math.h>

#define NN 50000
#define EE 800000
#define FF 32
#define HH 64
#define GG 2048
#define NLAYERS 4
#define EPSF 1e-6f
#define TILES 4

typedef __attribute__((ext_vector_type(8))) short short8;
typedef __attribute__((ext_vector_type(4))) float f32x4;
typedef __attribute__((ext_vector_type(4))) unsigned short us4;

__device__ __forceinline__ float elu_f(float x){ return x > 0.0f ? x : __expf(x) - 1.0f; }
__device__ __forceinline__ short f2bf_s(float x){
    __hip_bfloat16 h = __float2bfloat16(x);
    return *reinterpret_cast<short*>(&h);
}
__device__ __forceinline__ float bf2f(unsigned short u){
    unsigned int w = ((unsigned int)u) << 16;
    return *reinterpret_cast<float*>(&w);
}

// ---------------- in-degree count ----------------
__global__ __launch_bounds__(256) void k_count(const int* __restrict__ ei, int* __restrict__ counts)
{
    int e = blockIdx.x*256 + threadIdx.x;
    if (e >= EE) return;
    atomicAdd(&counts[ei[EE+e]], 1);
}

// ---------------- exclusive scan over counts -> rowptr (single block) ----------------
__global__ __launch_bounds__(1024) void k_scan(const int* __restrict__ counts, int* __restrict__ rowptr)
{
    __shared__ int sh[1024];
    const int CH = (NN + 1023)/1024;  // 49
    int t = threadIdx.x;
    int start = t*CH;
    int end = min(start+CH, NN);
    int s = 0;
    for (int i=start; i<end; i++) s += counts[i];
    sh[t] = s; __syncthreads();
    for (int off=1; off<1024; off<<=1){
        int v = (t>=off) ? sh[t-off] : 0;
        __syncthreads();
        sh[t] += v;
        __syncthreads();
    }
    int run = sh[t] - s;   // exclusive prefix
    for (int i=start; i<end; i++){ rowptr[i] = run; run += counts[i]; }
    if (t==1023) rowptr[NN] = run;
}

// ---------------- CSR fill: geometry + edge inputs in dst-sorted order ----------------
__global__ __launch_bounds__(256) void k_fill(
    const int* __restrict__ ei, const float* __restrict__ pos, const float* __restrict__ eattr,
    const int* __restrict__ rowptr, int* __restrict__ cursor,
    int* __restrict__ esrc, float* __restrict__ ein8)
{
    int e = blockIdx.x*256 + threadIdx.x;
    if (e >= EE) return;
    int src = ei[e], dst = ei[EE+e];
    float dx = pos[dst*3+0]-pos[src*3+0];
    float dy = pos[dst*3+1]-pos[src*3+1];
    float dz = pos[dst*3+2]-pos[src*3+2];
    float d = sqrtf(dx*dx+dy*dy+dz*dz+EPSF);
    float inv = 1.0f/d;
    int slot = rowptr[dst] + atomicAdd(&cursor[dst], 1);
    esrc[slot] = src;
    float4* p = (float4*)(ein8 + (size_t)slot*8);
    p[0] = make_float4(d, eattr[e*4+0], eattr[e*4+1], eattr[e*4+2]);
    p[1] = make_float4(eattr[e*4+3], dx*inv, dy*inv, dz*inv);
}

// ---------------- node embedding (fp32 master + packed bf16 quad gather copy) ----------------
__global__ __launch_bounds__(256) void k_embed(
    const float* __restrict__ x, const float* __restrict__ pos,
    const float* __restrict__ W_es, const float* __restrict__ b_es,
    const float* __restrict__ W_ev,
    float* __restrict__ ns, float* __restrict__ nv, __hip_bfloat16* __restrict__ nbf)
{
    int tid = blockIdx.x*256 + threadIdx.x;
    if (tid >= NN*FF) return;
    int n = tid >> 5, f = tid & 31;
    float x0=x[n*5+0], x1=x[n*5+1], x2=x[n*5+2], x3=x[n*5+3], x4=x[n*5+4];
    float s  = b_es[f] + x0*W_es[f] + x1*W_es[32+f] + x2*W_es[64+f] + x3*W_es[96+f] + x4*W_es[128+f];
    float vm =           x0*W_ev[f] + x1*W_ev[32+f] + x2*W_ev[64+f] + x3*W_ev[96+f] + x4*W_ev[128+f];
    float v0 = vm*pos[n*3+0], v1 = vm*pos[n*3+1], v2 = vm*pos[n*3+2];
    ns[tid] = s;
    nv[n*96+f*3+0] = v0;
    nv[n*96+f*3+1] = v1;
    nv[n*96+f*3+2] = v2;
    us4 q;
    q[0] = (unsigned short)f2bf_s(s);
    q[1] = (unsigned short)f2bf_s(v0);
    q[2] = (unsigned short)f2bf_s(v1);
    q[3] = (unsigned short)f2bf_s(v2);
    *(us4*)((unsigned short*)nbf + (size_t)n*128 + f*4) = q;
}

// ---------------- W2 transpose -> bf16: [l][k(64)][j(96)] -> [l][j(96)][k(64)] ----------------
__global__ __launch_bounds__(256) void k_transpose(const float* __restrict__ W2, __hip_bfloat16* __restrict__ W2bf)
{
    int tid = blockIdx.x*256 + threadIdx.x;
    if (tid >= NLAYERS*6144) return;
    int l = tid / 6144; int r = tid - l*6144;
    int j = r >> 6; int k = r & 63;
    W2bf[l*6144 + j*64 + k] = __float2bfloat16(W2[l*6144 + k*96 + j]);
}

// ---------------- W_inv transpose -> bf16: [k(64)][n(128)] -> [n(128)][k(64)] ----------------
__global__ __launch_bounds__(256) void k_transposeW(const float* __restrict__ W_inv, __hip_bfloat16* __restrict__ WinvT)
{
    int tid = blockIdx.x*256 + threadIdx.x;
    if (tid >= 8192) return;
    int n = tid >> 6, k = tid & 63;
    WinvT[n*64 + k] = __float2bfloat16(W_inv[k*128 + n]);
}

// ---------------- edge MLP via MFMA -> bf16 h rows [E][96] (edge-major) ----------------
// cstage rows padded to 104 shorts (208B, 16B-aligned) -> cooperative store as
// 3 x float4 (16B/lane, coalescing sweet spot) instead of 6 x float2.
__global__ __launch_bounds__(256) void k_mlp_mfma(
    const float* __restrict__ ein8,
    const float* __restrict__ W1l, const float* __restrict__ b1l,
    const __hip_bfloat16* __restrict__ W2bfl, const float* __restrict__ b2l,
    __hip_bfloat16* __restrict__ hbuf)
{
    __shared__ __align__(16) __hip_bfloat16 cstage[2][64][104];   // 2 x 13.3 KB
    const int tid  = threadIdx.x;
    const int lane = tid & 63;
    const int wave = tid >> 6;
    const int m    = lane & 15;
    const int quad = lane >> 4;

    for (int t=0; t<TILES; t++){
        const long long blockbase = ((long long)blockIdx.x*TILES + t) * 64;
        const long long edge = blockbase + wave*16 + m;

        const float4* p = (const float4*)(ein8 + edge*8);
        float4 q0 = p[0], q1 = p[1];
        float e0=q0.x, e1=q0.y, e2=q0.z, e3=q0.w, e4=q1.x;

        short8 afrag[2];
        #pragma unroll
        for (int s=0;s<2;s++){
            #pragma unroll
            for (int j=0;j<8;j++){
                int k = s*32 + quad*8 + j;
                float a = b1l[k] + e0*W1l[k] + e1*W1l[64+k] + e2*W1l[128+k]
                                 + e3*W1l[192+k] + e4*W1l[256+k];
                afrag[s][j] = f2bf_s(elu_f(a));
            }
        }

        f32x4 acc[6];
        #pragma unroll
        for (int u=0;u<6;u++) acc[u] = (f32x4){0.f,0.f,0.f,0.f};

        #pragma unroll
        for (int s=0;s<2;s++){
            #pragma unroll
            for (int u=0;u<6;u++){
                int n = u*16 + m;
                short8 bfrag = *(const short8*)(W2bfl + n*64 + s*32 + quad*8);
                acc[u] = __builtin_amdgcn_mfma_f32_16x16x32_bf16(afrag[s], bfrag, acc[u], 0, 0, 0);
            }
        }

        __hip_bfloat16 (*cs)[104] = cstage[t&1];
        #pragma unroll
        for (int u=0;u<6;u++){
            int n = u*16 + m;
            float bias = b2l[n];
            #pragma unroll
            for (int r=0;r<4;r++){
                cs[wave*16 + quad*4 + r][n] = __float2bfloat16(acc[u][r] + bias);
            }
        }
        __syncthreads();

        // cooperative edge-major store: 64 rows x 96 bf16 = 768 16B-chunks
        #pragma unroll
        for (int it=0; it<3; it++){
            int flat = it*256 + tid;
            int e = flat / 12, seg = flat % 12;
            float4 val = *(const float4*)&cs[e][seg*8];
            *(float4*)(hbuf + (blockbase + e)*96 + seg*8) = val;
        }
    }
}

// ---------------- CSR gather-aggregate + node update (no atomics) ----------------
// 32 lanes/node (R11 config: 32 VGPR, 66% occ). DEPTH-2 branchless pipeline:
// two slots staged in registers, prefetch slot+2 clamped to last (duplicate
// tail loads hit L1). Covers the esrc->nbf two-hop gather latency better
// than depth-1 while staying well under the R10 occupancy cliff.
__global__ __launch_bounds__(256) void k_agg(
    const int* __restrict__ rowptr, const int* __restrict__ esrc,
    const float* __restrict__ ein8, const __hip_bfloat16* __restrict__ hbuf,
    float* __restrict__ ns, float* __restrict__ nv,
    const __hip_bfloat16* __restrict__ nbfi,
    const float* __restrict__ Wsl, const float* __restrict__ Wvl,
    __hip_bfloat16* __restrict__ nbfo)
{
    int tid = blockIdx.x*256 + threadIdx.x;
    int n = tid >> 5, f = tid & 31;
    if (n >= NN) return;
    int beg = rowptr[n], end = rowptr[n+1];
    float as=0.f, a0=0.f, a1=0.f, a2=0.f;
    if (beg < end){
        const unsigned short* hb = (const unsigned short*)hbuf;
        const unsigned short* nb = (const unsigned short*)nbfi;
        const int last = end - 1;
        int sB = min(beg+1, last);
        // stage A (= beg) and stage B (= beg+1 clamped)
        float4 uA = *(const float4*)(ein8 + (size_t)beg*8 + 4);
        size_t hoA = (size_t)beg*96;
        unsigned short hxA=hb[hoA+f], hyA=hb[hoA+32+f], hzA=hb[hoA+64+f];
        us4 nqA = *(const us4*)(nb + (size_t)esrc[beg]*128 + f*4);
        float4 uB = *(const float4*)(ein8 + (size_t)sB*8 + 4);
        size_t hoB = (size_t)sB*96;
        unsigned short hxB=hb[hoB+f], hyB=hb[hoB+32+f], hzB=hb[hoB+64+f];
        us4 nqB = *(const us4*)(nb + (size_t)esrc[sB]*128 + f*4);
        for (int slot=beg; slot<end; slot++){
            int pp = min(slot+2, last);
            float4 uP = *(const float4*)(ein8 + (size_t)pp*8 + 4);
            size_t hoP = (size_t)pp*96;
            unsigned short hxP=hb[hoP+f], hyP=hb[hoP+32+f], hzP=hb[hoP+64+f];
            us4 nqP = *(const us4*)(nb + (size_t)esrc[pp]*128 + f*4);
            // consume stage A
            float gs = bf2f(hxA), gv = bf2f(hyA), gsv = bf2f(hzA);
            float s  = bf2f(nqA[0]);
            float v0 = bf2f(nqA[1]), v1 = bf2f(nqA[2]), v2 = bf2f(nqA[3]);
            float c = gsv*s;
            as += gs*s;
            a0 += gv*v0 + c*uA.y;
            a1 += gv*v1 + c*uA.z;
            a2 += gv*v2 + c*uA.w;
            // rotate stages
            uA=uB; hxA=hxB; hyA=hyB; hzA=hzB; nqA=nqB;
            uB=uP; hxB=hxP; hyB=hyP; hzB=hzP; nqB=nqP;
        }
    }
    float invd = 1.f/fmaxf((float)(end-beg), 1.f);
    as*=invd; a0*=invd; a1*=invd; a2*=invd;
    float os=0.f, o0=0.f, o1=0.f, o2=0.f;
    #pragma unroll
    for (int k=0;k<FF;k++){
        float bs = __shfl(as, k, 32);
        float b0 = __shfl(a0, k, 32);
        float b1 = __shfl(a1, k, 32);
        float b2 = __shfl(a2, k, 32);
        float ws = Wsl[k*32+f];
        float wv = Wvl[k*32+f];
        os += bs*ws; o0 += b0*wv; o1 += b1*wv; o2 += b2*wv;
    }
    float sn = ns[n*32+f] + elu_f(os);
    float w0 = nv[n*96+f*3+0] + o0;
    float w1 = nv[n*96+f*3+1] + o1;
    float w2 = nv[n*96+f*3+2] + o2;
    ns[n*32+f] = sn;
    nv[n*96+f*3+0] = w0;
    nv[n*96+f*3+1] = w1;
    nv[n*96+f*3+2] = w2;
    us4 q;
    q[0] = (unsigned short)f2bf_s(sn);
    q[1] = (unsigned short)f2bf_s(w0);
    q[2] = (unsigned short)f2bf_s(w1);
    q[3] = (unsigned short)f2bf_s(w2);
    *(us4*)((unsigned short*)nbfo + (size_t)n*128 + f*4) = q;
}

// ---------------- graph boundaries via binary search (batch is sorted) ----------------
__global__ __launch_bounds__(256) void k_gbounds(const int* __restrict__ batch, int* __restrict__ gstart)
{
    int g = blockIdx.x*256 + threadIdx.x;
    if (g > GG) return;
    int lo = 0, hi = NN;
    while (lo < hi){
        int mid = (lo+hi) >> 1;
        if (batch[mid] < g) lo = mid+1; else hi = mid;
    }
    gstart[g] = lo;
}

// ---------------- invariant map via MFMA: inv[N,128] = feat[N,64] @ W_inv (no bias) ----------------
__global__ __launch_bounds__(256) void k_invgemm(
    const float* __restrict__ ns, const float* __restrict__ nv,
    const __hip_bfloat16* __restrict__ WinvT,   // [128][64] bf16
    float* __restrict__ inv)                    // [N][128] fp32
{
    const int tid  = threadIdx.x;
    const int lane = tid & 63;
    const int wave = tid >> 6;
    const int m    = lane & 15;
    const int quad = lane >> 4;
    const int tilebase = blockIdx.x*64 + wave*16;
    const int node = tilebase + m;
    const bool valid = node < NN;

    short8 afrag[2];
    #pragma unroll
    for (int j=0;j<8;j++){
        int k = quad*8 + j;            // 0..31
        float fs = valid ? ns[(size_t)node*32 + k] : 0.f;
        afrag[0][j] = f2bf_s(fs);
        float v0 = valid ? nv[(size_t)node*96 + k*3+0] : 0.f;
        float v1 = valid ? nv[(size_t)node*96 + k*3+1] : 0.f;
        float v2 = valid ? nv[(size_t)node*96 + k*3+2] : 0.f;
        afrag[1][j] = f2bf_s(sqrtf(v0*v0+v1*v1+v2*v2+EPSF));
    }
    f32x4 acc[8];
    #pragma unroll
    for (int t=0;t<8;t++) acc[t] = (f32x4){0.f,0.f,0.f,0.f};
    #pragma unroll
    for (int s=0;s<2;s++){
        #pragma unroll
        for (int t=0;t<8;t++){
            short8 bfrag = *(const short8*)(WinvT + (t*16+m)*64 + s*32 + quad*8);
            acc[t] = __builtin_amdgcn_mfma_f32_16x16x32_bf16(afrag[s], bfrag, acc[t], 0, 0, 0);
        }
    }
    #pragma unroll
    for (int r=0;r<4;r++){
        int nrow = tilebase + quad*4 + r;
        if (nrow < NN){
            #pragma unroll
            for (int t=0;t<8;t++){
                inv[(size_t)nrow*128 + t*16 + m] = acc[t][r];
            }
        }
    }
}

// ---------------- graph mean pool over inv (coalesced, no LDS/sync) ----------------
__global__ __launch_bounds__(128) void k_pool(
    const int* __restrict__ gstart, const float* __restrict__ inv,
    const float* __restrict__ b_inv, float* __restrict__ xg)
{
    int g = blockIdx.x, j = threadIdx.x;
    int beg = gstart[g], end = gstart[g+1];
    float acc = 0.f;
    for (int n=beg; n<end; n++) acc += inv[(size_t)n*128 + j];
    int cnt = end - beg;
    float cp = fmaxf((float)cnt, 1.f);
    xg[g*128+j] = acc/cp + b_inv[j]*((float)cnt/cp);
}

// ---------------- per-column mean/rstd over G rows ----------------
__global__ __launch_bounds__(256) void k_colstats(
    const float* __restrict__ in, float* __restrict__ mean, float* __restrict__ rstd)
{
    int j = blockIdx.x;
    float s=0.f, q=0.f;
    for (int g=threadIdx.x; g<GG; g+=256){
        float x = in[g*128+j];
        s += x; q += x*x;
    }
    __shared__ float rs[256], rq[256];
    rs[threadIdx.x]=s; rq[threadIdx.x]=q;
    __syncthreads();
    for (int st=128; st>0; st>>=1){
        if (threadIdx.x < st){ rs[threadIdx.x]+=rs[threadIdx.x+st]; rq[threadIdx.x]+=rq[threadIdx.x+st]; }
        __syncthreads();
    }
    if (threadIdx.x==0){
        float m = rs[0]/(float)GG;
        float v = rq[0]/(float)GG - m*m;
        mean[j]=m; rstd[j]=rsqrtf(v+1e-5f);
    }
}

// ---------------- BN1 + ELU + FC1 ----------------
__global__ __launch_bounds__(128) void k_fc1(
    const float* __restrict__ xg, const float* __restrict__ mean, const float* __restrict__ rstd,
    const float* __restrict__ g1, const float* __restrict__ be1,
    const float* __restrict__ Wf1, const float* __restrict__ bf1,
    float* __restrict__ z1)
{
    int g = blockIdx.x, j = threadIdx.x;
    __shared__ float a[128];
    float xin = xg[g*128+j];
    a[j] = elu_f((xin-mean[j])*rstd[j]*g1[j]+be1[j]);
    __syncthreads();
    float z = bf1[j];
    #pragma unroll 8
    for (int k=0;k<128;k++) z += a[k]*Wf1[k*128+j];
    z1[g*128+j] = z;
}

// ---------------- BN2 + ELU + FC2 -> out ----------------
__global__ __launch_bounds__(128) void k_out(
    const float* __restrict__ z1, const float* __restrict__ mean, const float* __restrict__ rstd,
    const float* __restrict__ g2, const float* __restrict__ be2,
    const float* __restrict__ Wf2, const float* __restrict__ bf2,
    float* __restrict__ out)
{
    int g = blockIdx.x, j = threadIdx.x;
    float a = elu_f((z1[g*128+j]-mean[j])*rstd[j]*g2[j]+be2[j]) * Wf2[j];
    __shared__ float red[128];
    red[j]=a; __syncthreads();
    for (int st=64; st>0; st>>=1){
        if (j<st) red[j]+=red[j+st];
        __syncthreads();
    }
    if (j==0) out[g] = red[0] + bf2[0];
}

extern "C" void kernel_launch(void* const* d_in, const int* in_sizes, int n_in,
                              void* d_out, int out_size, void* d_ws, size_t ws_size,
                              hipStream_t stream)
{
    const float* x      = (const float*)d_in[0];
    const float* pos    = (const float*)d_in[1];
    const int*   ei     = (const int*)d_in[2];
    const float* eattr  = (const float*)d_in[3];
    const int*   batch  = (const int*)d_in[4];
    const float* W_es   = (const float*)d_in[5];
    const float* b_es   = (const float*)d_in[6];
    const float* W_ev   = (const float*)d_in[7];
    const float* W1     = (const float*)d_in[8];
    const float* b1     = (const float*)d_in[9];
    const float* W2     = (const float*)d_in[10];
    const float* b2     = (const float*)d_in[11];
    const float* Ws     = (const float*)d_in[12];
    const float* Wv     = (const float*)d_in[13];
    const float* W_inv  = (const float*)d_in[14];
    const float* b_inv  = (const float*)d_in[15];
    const float* g1     = (const float*)d_in[16];
    const float* be1    = (const float*)d_in[17];
    const float* Wf1    = (const float*)d_in[18];
    const float* bf1    = (const float*)d_in[19];
    const float* g2     = (const float*)d_in[20];
    const float* be2    = (const float*)d_in[21];
    const float* Wf2    = (const float*)d_in[22];
    const float* bf2    = (const float*)d_in[23];
    float* out = (float*)d_out;

    // ---- workspace layout (4-byte units, 64B aligned blocks) ----
    // Total ~236.4 MB (< ~256 MiB ws_size; R7 lesson). inv[N][128] fp32
    // (25.6 MB) ALIASES hbuf — hbuf is dead after the last k_agg.
    char* base = (char*)d_ws;
    size_t off = 0;
    auto alloc = [&](size_t elems4) { // elems in 4-byte units
        void* p = base + off;
        off += ((elems4*4 + 63) & ~size_t(63));
        return p;
    };
    int*   counts = (int*)  alloc(50000);       // zeroed
    int*   cursor = (int*)  alloc(50000);       // zeroed
    size_t zero_bytes = off;
    int*   rowptr = (int*)  alloc(50001);
    int*   esrc   = (int*)  alloc(800000);
    float* ein8   = (float*)alloc(6400000);     // [E][8]: d,a0..a3 | a3,u0,u1,u2
    float* ns     = (float*)alloc(1600000);     // fp32 master, in-place residual
    float* nv     = (float*)alloc(4800000);
    __hip_bfloat16* nbfA = (__hip_bfloat16*)alloc(3200000); // [N][32][4] bf16 quads = 12.8 MB
    __hip_bfloat16* nbfB = (__hip_bfloat16*)alloc(3200000);
    __hip_bfloat16* W2bf = (__hip_bfloat16*)alloc(12288);   // NL*96*64 bf16
    __hip_bfloat16* WinvT= (__hip_bfloat16*)alloc(4096);    // [128][64] bf16
    int*   gstart = (int*)  alloc(2049);
    float* xg     = (float*)alloc(262144);
    float* z1     = (float*)alloc(262144);
    float* m1     = (float*)alloc(128);
    float* r1     = (float*)alloc(128);
    float* m2     = (float*)alloc(128);
    float* r2     = (float*)alloc(128);
    __hip_bfloat16* hbuf = (__hip_bfloat16*)alloc(38400000); // [E][96] bf16 edge-major
    float* inv    = (float*)hbuf;               // alias: used only after layers

    hipMemsetAsync(d_ws, 0, zero_bytes, stream);

    // ---- setup: CSR build + embedding + weight transposes ----
    k_count    <<<EE/256, 256, 0, stream>>>(ei, counts);
    k_scan     <<<1, 1024, 0, stream>>>(counts, rowptr);
    k_fill     <<<EE/256, 256, 0, stream>>>(ei, pos, eattr, rowptr, cursor, esrc, ein8);
    k_embed    <<<NN*FF/256, 256, 0, stream>>>(x, pos, W_es, b_es, W_ev, ns, nv, nbfA);
    k_transpose<<<(NLAYERS*6144+255)/256, 256, 0, stream>>>(W2, W2bf);
    k_transposeW<<<(8192+255)/256, 256, 0, stream>>>(W_inv, WinvT);

    // ---- message-passing layers (bf16 gather copy double-buffered) ----
    for (int l=0; l<NLAYERS; l++){
        const __hip_bfloat16* nbfi = (l&1) ? nbfB : nbfA;
        __hip_bfloat16* nbfo = (l&1) ? nbfA : nbfB;
        k_mlp_mfma<<<EE/(64*TILES), 256, 0, stream>>>(ein8,
            W1 + l*320, b1 + l*64, W2bf + l*6144, b2 + l*96, hbuf);
        k_agg<<<(NN*32+255)/256, 256, 0, stream>>>(rowptr, esrc, ein8, hbuf,
            ns, nv, nbfi, Ws + l*1024, Wv + l*1024, nbfo);
    }
    // fp32 ns/nv hold final node features (in-place updates)

    // ---- invariant map (MFMA) + pooling + head ----
    k_gbounds <<<(GG+1+255)/256, 256, 0, stream>>>(batch, gstart);
    k_invgemm <<<(NN+63)/64, 256, 0, stream>>>(ns, nv, WinvT, inv);
    k_pool    <<<GG, 128, 0, stream>>>(gstart, inv, b_inv, xg);
    k_colstats<<<128, 256, 0, stream>>>(xg, m1, r1);
    k_fc1     <<<GG, 128, 0, stream>>>(xg, m1, r1, g1, be1, Wf1, bf1, z1);
    k_colstats<<<128, 256, 0, stream>>>(z1, m2, r2);
    k_out     <<<GG, 128, 0, stream>>>(z1, m2, r2, g2, be2, Wf2, bf2, out);
}

// Round 13
// 884.115 us; speedup vs baseline: 1.4147x; 1.0316x over previous
//
#include <hip/hip_runtime.h>
#include <hip/hip_bf16.h>
#include <math.h>

#define NN 50000
#define EE 800000
#define FF 32
#define HH 64
#define GG 2048
#define NLAYERS 4
#define EPSF 1e-6f
#define TILES 4

typedef __attribute__((ext_vector_type(8))) short short8;
typedef __attribute__((ext_vector_type(4))) float f32x4;
typedef __attribute__((ext_vector_type(4))) unsigned short us4;

__device__ __forceinline__ float elu_f(float x){ return x > 0.0f ? x : __expf(x) - 1.0f; }
__device__ __forceinline__ short f2bf_s(float x){
    __hip_bfloat16 h = __float2bfloat16(x);
    return *reinterpret_cast<short*>(&h);
}
__device__ __forceinline__ float bf2f(unsigned short u){
    unsigned int w = ((unsigned int)u) << 16;
    return *reinterpret_cast<float*>(&w);
}

// ---------------- in-degree count ----------------
__global__ __launch_bounds__(256) void k_count(const int* __restrict__ ei, int* __restrict__ counts)
{
    int e = blockIdx.x*256 + threadIdx.x;
    if (e >= EE) return;
    atomicAdd(&counts[ei[EE+e]], 1);
}

// ---------------- exclusive scan over counts -> rowptr (single block) ----------------
__global__ __launch_bounds__(1024) void k_scan(const int* __restrict__ counts, int* __restrict__ rowptr)
{
    __shared__ int sh[1024];
    const int CH = (NN + 1023)/1024;  // 49
    int t = threadIdx.x;
    int start = t*CH;
    int end = min(start+CH, NN);
    int s = 0;
    for (int i=start; i<end; i++) s += counts[i];
    sh[t] = s; __syncthreads();
    for (int off=1; off<1024; off<<=1){
        int v = (t>=off) ? sh[t-off] : 0;
        __syncthreads();
        sh[t] += v;
        __syncthreads();
    }
    int run = sh[t] - s;   // exclusive prefix
    for (int i=start; i<end; i++){ rowptr[i] = run; run += counts[i]; }
    if (t==1023) rowptr[NN] = run;
}

// ---------------- CSR fill: geometry + edge inputs in dst-sorted order ----------------
__global__ __launch_bounds__(256) void k_fill(
    const int* __restrict__ ei, const float* __restrict__ pos, const float* __restrict__ eattr,
    const int* __restrict__ rowptr, int* __restrict__ cursor,
    int* __restrict__ esrc, float* __restrict__ ein8)
{
    int e = blockIdx.x*256 + threadIdx.x;
    if (e >= EE) return;
    int src = ei[e], dst = ei[EE+e];
    float dx = pos[dst*3+0]-pos[src*3+0];
    float dy = pos[dst*3+1]-pos[src*3+1];
    float dz = pos[dst*3+2]-pos[src*3+2];
    float d = sqrtf(dx*dx+dy*dy+dz*dz+EPSF);
    float inv = 1.0f/d;
    int slot = rowptr[dst] + atomicAdd(&cursor[dst], 1);
    esrc[slot] = src;
    float4* p = (float4*)(ein8 + (size_t)slot*8);
    p[0] = make_float4(d, eattr[e*4+0], eattr[e*4+1], eattr[e*4+2]);
    p[1] = make_float4(eattr[e*4+3], dx*inv, dy*inv, dz*inv);
}

// ---------------- node embedding (fp32 master + packed bf16 quad gather copy) ----------------
__global__ __launch_bounds__(256) void k_embed(
    const float* __restrict__ x, const float* __restrict__ pos,
    const float* __restrict__ W_es, const float* __restrict__ b_es,
    const float* __restrict__ W_ev,
    float* __restrict__ ns, float* __restrict__ nv, __hip_bfloat16* __restrict__ nbf)
{
    int tid = blockIdx.x*256 + threadIdx.x;
    if (tid >= NN*FF) return;
    int n = tid >> 5, f = tid & 31;
    float x0=x[n*5+0], x1=x[n*5+1], x2=x[n*5+2], x3=x[n*5+3], x4=x[n*5+4];
    float s  = b_es[f] + x0*W_es[f] + x1*W_es[32+f] + x2*W_es[64+f] + x3*W_es[96+f] + x4*W_es[128+f];
    float vm =           x0*W_ev[f] + x1*W_ev[32+f] + x2*W_ev[64+f] + x3*W_ev[96+f] + x4*W_ev[128+f];
    float v0 = vm*pos[n*3+0], v1 = vm*pos[n*3+1], v2 = vm*pos[n*3+2];
    ns[tid] = s;
    nv[n*96+f*3+0] = v0;
    nv[n*96+f*3+1] = v1;
    nv[n*96+f*3+2] = v2;
    us4 q;
    q[0] = (unsigned short)f2bf_s(s);
    q[1] = (unsigned short)f2bf_s(v0);
    q[2] = (unsigned short)f2bf_s(v1);
    q[3] = (unsigned short)f2bf_s(v2);
    *(us4*)((unsigned short*)nbf + (size_t)n*128 + f*4) = q;
}

// ---------------- fused weight transposes -> bf16 ----------------
// W2: [l][k(64)][j(96)] -> W2bf [l][j(96)][k(64)]   (24576 elems)
// W_inv: [k(64)][n(128)] -> WinvT [n(128)][k(64)]   (8192 elems)
__global__ __launch_bounds__(256) void k_transpose(
    const float* __restrict__ W2, __hip_bfloat16* __restrict__ W2bf,
    const float* __restrict__ W_inv, __hip_bfloat16* __restrict__ WinvT)
{
    int tid = blockIdx.x*256 + threadIdx.x;
    if (tid < NLAYERS*6144){
        int l = tid / 6144; int r = tid - l*6144;
        int j = r >> 6; int k = r & 63;
        W2bf[l*6144 + j*64 + k] = __float2bfloat16(W2[l*6144 + k*96 + j]);
    } else if (tid < NLAYERS*6144 + 8192){
        int r = tid - NLAYERS*6144;
        int n = r >> 6, k = r & 63;
        WinvT[n*64 + k] = __float2bfloat16(W_inv[k*128 + n]);
    }
}

// ---------------- edge MLP via MFMA -> bf16 h rows [E][96] (edge-major) ----------------
__global__ __launch_bounds__(256) void k_mlp_mfma(
    const float* __restrict__ ein8,
    const float* __restrict__ W1l, const float* __restrict__ b1l,
    const __hip_bfloat16* __restrict__ W2bfl, const float* __restrict__ b2l,
    __hip_bfloat16* __restrict__ hbuf)
{
    __shared__ __align__(16) __hip_bfloat16 cstage[2][64][104];   // 2 x 13.3 KB
    const int tid  = threadIdx.x;
    const int lane = tid & 63;
    const int wave = tid >> 6;
    const int m    = lane & 15;
    const int quad = lane >> 4;

    for (int t=0; t<TILES; t++){
        const long long blockbase = ((long long)blockIdx.x*TILES + t) * 64;
        const long long edge = blockbase + wave*16 + m;

        const float4* p = (const float4*)(ein8 + edge*8);
        float4 q0 = p[0], q1 = p[1];
        float e0=q0.x, e1=q0.y, e2=q0.z, e3=q0.w, e4=q1.x;

        short8 afrag[2];
        #pragma unroll
        for (int s=0;s<2;s++){
            #pragma unroll
            for (int j=0;j<8;j++){
                int k = s*32 + quad*8 + j;
                float a = b1l[k] + e0*W1l[k] + e1*W1l[64+k] + e2*W1l[128+k]
                                 + e3*W1l[192+k] + e4*W1l[256+k];
                afrag[s][j] = f2bf_s(elu_f(a));
            }
        }

        f32x4 acc[6];
        #pragma unroll
        for (int u=0;u<6;u++) acc[u] = (f32x4){0.f,0.f,0.f,0.f};

        #pragma unroll
        for (int s=0;s<2;s++){
            #pragma unroll
            for (int u=0;u<6;u++){
                int n = u*16 + m;
                short8 bfrag = *(const short8*)(W2bfl + n*64 + s*32 + quad*8);
                acc[u] = __builtin_amdgcn_mfma_f32_16x16x32_bf16(afrag[s], bfrag, acc[u], 0, 0, 0);
            }
        }

        __hip_bfloat16 (*cs)[104] = cstage[t&1];
        #pragma unroll
        for (int u=0;u<6;u++){
            int n = u*16 + m;
            float bias = b2l[n];
            #pragma unroll
            for (int r=0;r<4;r++){
                cs[wave*16 + quad*4 + r][n] = __float2bfloat16(acc[u][r] + bias);
            }
        }
        __syncthreads();

        // cooperative edge-major store: 64 rows x 96 bf16 = 768 16B-chunks
        #pragma unroll
        for (int it=0; it<3; it++){
            int flat = it*256 + tid;
            int e = flat / 12, seg = flat % 12;
            float4 val = *(const float4*)&cs[e][seg*8];
            *(float4*)(hbuf + (blockbase + e)*96 + seg*8) = val;
        }
    }
}

// ---------------- CSR gather-aggregate + node update (no atomics) ----------------
// 32 lanes/node. Blocked unroll-4: issue ALL loads for 4 slots back-to-back
// (~24 outstanding incl. the esrc->nbf chains), then consume 4. One gather
// latency stall per 4 slots (R12 post-mortem: depth-2 rotation covered only
// ~60cyc of a ~500cyc chain; more MLP = more outstanding loads, not rotation).
__global__ __launch_bounds__(256) void k_agg(
    const int* __restrict__ rowptr, const int* __restrict__ esrc,
    const float* __restrict__ ein8, const __hip_bfloat16* __restrict__ hbuf,
    float* __restrict__ ns, float* __restrict__ nv,
    const __hip_bfloat16* __restrict__ nbfi,
    const float* __restrict__ Wsl, const float* __restrict__ Wvl,
    __hip_bfloat16* __restrict__ nbfo)
{
    int tid = blockIdx.x*256 + threadIdx.x;
    int n = tid >> 5, f = tid & 31;
    if (n >= NN) return;
    int beg = rowptr[n], end = rowptr[n+1];
    float as=0.f, a0=0.f, a1=0.f, a2=0.f;
    {
        const unsigned short* hb = (const unsigned short*)hbuf;
        const unsigned short* nb = (const unsigned short*)nbfi;
        const int last = end - 1;
        for (int sb=beg; sb<end; sb+=4){
            float4 u[4]; unsigned short hx[4],hy[4],hz[4]; us4 nq[4];
            #pragma unroll
            for (int j=0;j<4;j++){
                int sl = min(sb+j, last);
                u[j] = *(const float4*)(ein8 + (size_t)sl*8 + 4);
                size_t ho = (size_t)sl*96;
                hx[j]=hb[ho+f]; hy[j]=hb[ho+32+f]; hz[j]=hb[ho+64+f];
                nq[j] = *(const us4*)(nb + (size_t)esrc[sl]*128 + f*4);
            }
            #pragma unroll
            for (int j=0;j<4;j++){
                if (sb+j < end){
                    float gs = bf2f(hx[j]), gv = bf2f(hy[j]), gsv = bf2f(hz[j]);
                    float s  = bf2f(nq[j][0]);
                    float v0 = bf2f(nq[j][1]), v1 = bf2f(nq[j][2]), v2 = bf2f(nq[j][3]);
                    float c = gsv*s;
                    as += gs*s;
                    a0 += gv*v0 + c*u[j].y;
                    a1 += gv*v1 + c*u[j].z;
                    a2 += gv*v2 + c*u[j].w;
                }
            }
        }
    }
    float invd = 1.f/fmaxf((float)(end-beg), 1.f);
    as*=invd; a0*=invd; a1*=invd; a2*=invd;
    float os=0.f, o0=0.f, o1=0.f, o2=0.f;
    #pragma unroll
    for (int k=0;k<FF;k++){
        float bs = __shfl(as, k, 32);
        float b0 = __shfl(a0, k, 32);
        float b1 = __shfl(a1, k, 32);
        float b2 = __shfl(a2, k, 32);
        float ws = Wsl[k*32+f];
        float wv = Wvl[k*32+f];
        os += bs*ws; o0 += b0*wv; o1 += b1*wv; o2 += b2*wv;
    }
    float sn = ns[n*32+f] + elu_f(os);
    float w0 = nv[n*96+f*3+0] + o0;
    float w1 = nv[n*96+f*3+1] + o1;
    float w2 = nv[n*96+f*3+2] + o2;
    ns[n*32+f] = sn;
    nv[n*96+f*3+0] = w0;
    nv[n*96+f*3+1] = w1;
    nv[n*96+f*3+2] = w2;
    us4 q;
    q[0] = (unsigned short)f2bf_s(sn);
    q[1] = (unsigned short)f2bf_s(w0);
    q[2] = (unsigned short)f2bf_s(w1);
    q[3] = (unsigned short)f2bf_s(w2);
    *(us4*)((unsigned short*)nbfo + (size_t)n*128 + f*4) = q;
}

// ---------------- invariant map via MFMA: inv[N,128] = feat[N,64] @ W_inv (no bias) ----------------
__global__ __launch_bounds__(256) void k_invgemm(
    const float* __restrict__ ns, const float* __restrict__ nv,
    const __hip_bfloat16* __restrict__ WinvT,   // [128][64] bf16
    float* __restrict__ inv)                    // [N][128] fp32
{
    const int tid  = threadIdx.x;
    const int lane = tid & 63;
    const int wave = tid >> 6;
    const int m    = lane & 15;
    const int quad = lane >> 4;
    const int tilebase = blockIdx.x*64 + wave*16;
    const int node = tilebase + m;
    const bool valid = node < NN;

    short8 afrag[2];
    #pragma unroll
    for (int j=0;j<8;j++){
        int k = quad*8 + j;            // 0..31
        float fs = valid ? ns[(size_t)node*32 + k] : 0.f;
        afrag[0][j] = f2bf_s(fs);
        float v0 = valid ? nv[(size_t)node*96 + k*3+0] : 0.f;
        float v1 = valid ? nv[(size_t)node*96 + k*3+1] : 0.f;
        float v2 = valid ? nv[(size_t)node*96 + k*3+2] : 0.f;
        afrag[1][j] = f2bf_s(sqrtf(v0*v0+v1*v1+v2*v2+EPSF));
    }
    f32x4 acc[8];
    #pragma unroll
    for (int t=0;t<8;t++) acc[t] = (f32x4){0.f,0.f,0.f,0.f};
    #pragma unroll
    for (int s=0;s<2;s++){
        #pragma unroll
        for (int t=0;t<8;t++){
            short8 bfrag = *(const short8*)(WinvT + (t*16+m)*64 + s*32 + quad*8);
            acc[t] = __builtin_amdgcn_mfma_f32_16x16x32_bf16(afrag[s], bfrag, acc[t], 0, 0, 0);
        }
    }
    #pragma unroll
    for (int r=0;r<4;r++){
        int nrow = tilebase + quad*4 + r;
        if (nrow < NN){
            #pragma unroll
            for (int t=0;t<8;t++){
                inv[(size_t)nrow*128 + t*16 + m] = acc[t][r];
            }
        }
    }
}

// ---------------- graph mean pool over inv (binary-search bounds fused in) ----------------
__global__ __launch_bounds__(128) void k_pool(
    const int* __restrict__ batch, const float* __restrict__ inv,
    const float* __restrict__ b_inv, float* __restrict__ xg)
{
    int g = blockIdx.x, j = threadIdx.x;
    // all threads redundantly binary-search [beg,end) for graph g (sorted batch)
    int lo = 0, hi = NN;
    while (lo < hi){ int mid=(lo+hi)>>1; if (batch[mid] < g) lo=mid+1; else hi=mid; }
    int beg = lo;
    lo = 0; hi = NN;
    while (lo < hi){ int mid=(lo+hi)>>1; if (batch[mid] < g+1) lo=mid+1; else hi=mid; }
    int end = lo;
    float acc = 0.f;
    for (int n=beg; n<end; n++) acc += inv[(size_t)n*128 + j];
    int cnt = end - beg;
    float cp = fmaxf((float)cnt, 1.f);
    xg[g*128+j] = acc/cp + b_inv[j]*((float)cnt/cp);
}

// ---------------- per-column mean/rstd over G rows ----------------
__global__ __launch_bounds__(256) void k_colstats(
    const float* __restrict__ in, float* __restrict__ mean, float* __restrict__ rstd)
{
    int j = blockIdx.x;
    float s=0.f, q=0.f;
    for (int g=threadIdx.x; g<GG; g+=256){
        float x = in[g*128+j];
        s += x; q += x*x;
    }
    __shared__ float rs[256], rq[256];
    rs[threadIdx.x]=s; rq[threadIdx.x]=q;
    __syncthreads();
    for (int st=128; st>0; st>>=1){
        if (threadIdx.x < st){ rs[threadIdx.x]+=rs[threadIdx.x+st]; rq[threadIdx.x]+=rq[threadIdx.x+st]; }
        __syncthreads();
    }
    if (threadIdx.x==0){
        float m = rs[0]/(float)GG;
        float v = rq[0]/(float)GG - m*m;
        mean[j]=m; rstd[j]=rsqrtf(v+1e-5f);
    }
}

// ---------------- BN1 + ELU + FC1 ----------------
__global__ __launch_bounds__(128) void k_fc1(
    const float* __restrict__ xg, const float* __restrict__ mean, const float* __restrict__ rstd,
    const float* __restrict__ g1, const float* __restrict__ be1,
    const float* __restrict__ Wf1, const float* __restrict__ bf1,
    float* __restrict__ z1)
{
    int g = blockIdx.x, j = threadIdx.x;
    __shared__ float a[128];
    float xin = xg[g*128+j];
    a[j] = elu_f((xin-mean[j])*rstd[j]*g1[j]+be1[j]);
    __syncthreads();
    float z = bf1[j];
    #pragma unroll 8
    for (int k=0;k<128;k++) z += a[k]*Wf1[k*128+j];
    z1[g*128+j] = z;
}

// ---------------- BN2 + ELU + FC2 -> out ----------------
__global__ __launch_bounds__(128) void k_out(
    const float* __restrict__ z1, const float* __restrict__ mean, const float* __restrict__ rstd,
    const float* __restrict__ g2, const float* __restrict__ be2,
    const float* __restrict__ Wf2, const float* __restrict__ bf2,
    float* __restrict__ out)
{
    int g = blockIdx.x, j = threadIdx.x;
    float a = elu_f((z1[g*128+j]-mean[j])*rstd[j]*g2[j]+be2[j]) * Wf2[j];
    __shared__ float red[128];
    red[j]=a; __syncthreads();
    for (int st=64; st>0; st>>=1){
        if (j<st) red[j]+=red[j+st];
        __syncthreads();
    }
    if (j==0) out[g] = red[0] + bf2[0];
}

extern "C" void kernel_launch(void* const* d_in, const int* in_sizes, int n_in,
                              void* d_out, int out_size, void* d_ws, size_t ws_size,
                              hipStream_t stream)
{
    const float* x      = (const float*)d_in[0];
    const float* pos    = (const float*)d_in[1];
    const int*   ei     = (const int*)d_in[2];
    const float* eattr  = (const float*)d_in[3];
    const int*   batch  = (const int*)d_in[4];
    const float* W_es   = (const float*)d_in[5];
    const float* b_es   = (const float*)d_in[6];
    const float* W_ev   = (const float*)d_in[7];
    const float* W1     = (const float*)d_in[8];
    const float* b1     = (const float*)d_in[9];
    const float* W2     = (const float*)d_in[10];
    const float* b2     = (const float*)d_in[11];
    const float* Ws     = (const float*)d_in[12];
    const float* Wv     = (const float*)d_in[13];
    const float* W_inv  = (const float*)d_in[14];
    const float* b_inv  = (const float*)d_in[15];
    const float* g1     = (const float*)d_in[16];
    const float* be1    = (const float*)d_in[17];
    const float* Wf1    = (const float*)d_in[18];
    const float* bf1    = (const float*)d_in[19];
    const float* g2     = (const float*)d_in[20];
    const float* be2    = (const float*)d_in[21];
    const float* Wf2    = (const float*)d_in[22];
    const float* bf2    = (const float*)d_in[23];
    float* out = (float*)d_out;

    // ---- workspace layout (4-byte units, 64B aligned blocks) ----
    // Total ~236.4 MB (< ~256 MiB ws_size; R7 lesson). inv[N][128] fp32
    // (25.6 MB) ALIASES hbuf — hbuf is dead after the last k_agg.
    char* base = (char*)d_ws;
    size_t off = 0;
    auto alloc = [&](size_t elems4) { // elems in 4-byte units
        void* p = base + off;
        off += ((elems4*4 + 63) & ~size_t(63));
        return p;
    };
    int*   counts = (int*)  alloc(50000);       // zeroed
    int*   cursor = (int*)  alloc(50000);       // zeroed
    size_t zero_bytes = off;
    int*   rowptr = (int*)  alloc(50001);
    int*   esrc   = (int*)  alloc(800000);
    float* ein8   = (float*)alloc(6400000);     // [E][8]: d,a0..a3 | a3,u0,u1,u2
    float* ns     = (float*)alloc(1600000);     // fp32 master, in-place residual
    float* nv     = (float*)alloc(4800000);
    __hip_bfloat16* nbfA = (__hip_bfloat16*)alloc(3200000); // [N][32][4] bf16 quads = 12.8 MB
    __hip_bfloat16* nbfB = (__hip_bfloat16*)alloc(3200000);
    __hip_bfloat16* W2bf = (__hip_bfloat16*)alloc(12288);   // NL*96*64 bf16
    __hip_bfloat16* WinvT= (__hip_bfloat16*)alloc(4096);    // [128][64] bf16
    float* xg     = (float*)alloc(262144);
    float* z1     = (float*)alloc(262144);
    float* m1     = (float*)alloc(128);
    float* r1     = (float*)alloc(128);
    float* m2     = (float*)alloc(128);
    float* r2     = (float*)alloc(128);
    __hip_bfloat16* hbuf = (__hip_bfloat16*)alloc(38400000); // [E][96] bf16 edge-major
    float* inv    = (float*)hbuf;               // alias: used only after layers

    hipMemsetAsync(d_ws, 0, zero_bytes, stream);

    // ---- setup: CSR build + embedding + fused weight transpose ----
    k_count    <<<EE/256, 256, 0, stream>>>(ei, counts);
    k_scan     <<<1, 1024, 0, stream>>>(counts, rowptr);
    k_fill     <<<EE/256, 256, 0, stream>>>(ei, pos, eattr, rowptr, cursor, esrc, ein8);
    k_embed    <<<NN*FF/256, 256, 0, stream>>>(x, pos, W_es, b_es, W_ev, ns, nv, nbfA);
    k_transpose<<<(NLAYERS*6144+8192+255)/256, 256, 0, stream>>>(W2, W2bf, W_inv, WinvT);

    // ---- message-passing layers (bf16 gather copy double-buffered) ----
    for (int l=0; l<NLAYERS; l++){
        const __hip_bfloat16* nbfi = (l&1) ? nbfB : nbfA;
        __hip_bfloat16* nbfo = (l&1) ? nbfA : nbfB;
        k_mlp_mfma<<<EE/(64*TILES), 256, 0, stream>>>(ein8,
            W1 + l*320, b1 + l*64, W2bf + l*6144, b2 + l*96, hbuf);
        k_agg<<<(NN*32+255)/256, 256, 0, stream>>>(rowptr, esrc, ein8, hbuf,
            ns, nv, nbfi, Ws + l*1024, Wv + l*1024, nbfo);
    }
    // fp32 ns/nv hold final node features (in-place updates)

    // ---- invariant map (MFMA) + pooling + head ----
    k_invgemm <<<(NN+63)/64, 256, 0, stream>>>(ns, nv, WinvT, inv);
    k_pool    <<<GG, 128, 0, stream>>>(batch, inv, b_inv, xg);
    k_colstats<<<128, 256, 0, stream>>>(xg, m1, r1);
    k_fc1     <<<GG, 128, 0, stream>>>(xg, m1, r1, g1, be1, Wf1, bf1, z1);
    k_colstats<<<128, 256, 0, stream>>>(z1, m2, r2);
    k_out     <<<GG, 128, 0, stream>>>(z1, m2, r2, g2, be2, Wf2, bf2, out);
}

// Round 14
// 816.436 us; speedup vs baseline: 1.5320x; 1.0829x over previous
//
#include <hip/hip_runtime.h>
#include <hip/hip_bf16.h>
#include <math.h>

#define NN 50000
#define EE 800000
#define FF 32
#define HH 64
#define GG 2048
#define NLAYERS 4
#define EPSF 1e-6f
#define TILES 4
#define SCAN_BLOCKS ((NN + 255) / 256)   // 196

typedef __attribute__((ext_vector_type(8))) short short8;
typedef __attribute__((ext_vector_type(4))) float f32x4;
typedef __attribute__((ext_vector_type(4))) unsigned short us4;

__device__ __forceinline__ float elu_f(float x){ return x > 0.0f ? x : __expf(x) - 1.0f; }
__device__ __forceinline__ short f2bf_s(float x){
    __hip_bfloat16 h = __float2bfloat16(x);
    return *reinterpret_cast<short*>(&h);
}
__device__ __forceinline__ float bf2f(unsigned short u){
    unsigned int w = ((unsigned int)u) << 16;
    return *reinterpret_cast<float*>(&w);
}

// ---------------- in-degree count ----------------
__global__ __launch_bounds__(256) void k_count(const int* __restrict__ ei, int* __restrict__ counts)
{
    int e = blockIdx.x*256 + threadIdx.x;
    if (e >= EE) return;
    atomicAdd(&counts[ei[EE+e]], 1);
}

// ---------------- parallel scan phase 1: per-block sums ----------------
__global__ __launch_bounds__(256) void k_bsum(const int* __restrict__ counts, int* __restrict__ bsum)
{
    int i = blockIdx.x*256 + threadIdx.x;
    int v = (i < NN) ? counts[i] : 0;
    #pragma unroll
    for (int o=32; o>0; o>>=1) v += __shfl_down(v, o, 64);
    __shared__ int ws[4];
    if ((threadIdx.x & 63) == 0) ws[threadIdx.x >> 6] = v;
    __syncthreads();
    if (threadIdx.x == 0) bsum[blockIdx.x] = ws[0]+ws[1]+ws[2]+ws[3];
}

// ---------------- parallel scan phase 2: scan block sums (1 tiny block) ----------------
__global__ __launch_bounds__(256) void k_bscan(const int* __restrict__ bsum, int* __restrict__ boff,
                                               int* __restrict__ rowptr_last)
{
    int t = threadIdx.x;
    int v = (t < SCAN_BLOCKS) ? bsum[t] : 0;
    __shared__ int sh[256];
    sh[t] = v; __syncthreads();
    for (int o=1; o<256; o<<=1){
        int u = (t >= o) ? sh[t-o] : 0;
        __syncthreads();
        sh[t] += u;
        __syncthreads();
    }
    if (t < SCAN_BLOCKS) boff[t] = sh[t] - v;    // exclusive
    if (t == 255) rowptr_last[0] = sh[255];      // rowptr[NN] = total
}

// ---------------- parallel scan phase 3: per-block exclusive scan + offset ----------------
__global__ __launch_bounds__(256) void k_rowptr(const int* __restrict__ counts,
                                                const int* __restrict__ boff, int* __restrict__ rowptr)
{
    int i = blockIdx.x*256 + threadIdx.x;
    int t = threadIdx.x;
    int v = (i < NN) ? counts[i] : 0;
    __shared__ int sh[256];
    sh[t] = v; __syncthreads();
    for (int o=1; o<256; o<<=1){
        int u = (t >= o) ? sh[t-o] : 0;
        __syncthreads();
        sh[t] += u;
        __syncthreads();
    }
    if (i < NN) rowptr[i] = boff[blockIdx.x] + sh[t] - v;
}

// ---------------- CSR fill: geometry + edge inputs in dst-sorted order ----------------
__global__ __launch_bounds__(256) void k_fill(
    const int* __restrict__ ei, const float* __restrict__ pos, const float* __restrict__ eattr,
    const int* __restrict__ rowptr, int* __restrict__ cursor,
    int* __restrict__ esrc, float* __restrict__ ein8)
{
    int e = blockIdx.x*256 + threadIdx.x;
    if (e >= EE) return;
    int src = ei[e], dst = ei[EE+e];
    float dx = pos[dst*3+0]-pos[src*3+0];
    float dy = pos[dst*3+1]-pos[src*3+1];
    float dz = pos[dst*3+2]-pos[src*3+2];
    float d = sqrtf(dx*dx+dy*dy+dz*dz+EPSF);
    float inv = 1.0f/d;
    int slot = rowptr[dst] + atomicAdd(&cursor[dst], 1);
    esrc[slot] = src;
    float4* p = (float4*)(ein8 + (size_t)slot*8);
    p[0] = make_float4(d, eattr[e*4+0], eattr[e*4+1], eattr[e*4+2]);
    p[1] = make_float4(eattr[e*4+3], dx*inv, dy*inv, dz*inv);
}

// ---------------- node embedding (fp32 master + packed bf16 quad gather copy) ----------------
__global__ __launch_bounds__(256) void k_embed(
    const float* __restrict__ x, const float* __restrict__ pos,
    const float* __restrict__ W_es, const float* __restrict__ b_es,
    const float* __restrict__ W_ev,
    float* __restrict__ ns, float* __restrict__ nv, __hip_bfloat16* __restrict__ nbf)
{
    int tid = blockIdx.x*256 + threadIdx.x;
    if (tid >= NN*FF) return;
    int n = tid >> 5, f = tid & 31;
    float x0=x[n*5+0], x1=x[n*5+1], x2=x[n*5+2], x3=x[n*5+3], x4=x[n*5+4];
    float s  = b_es[f] + x0*W_es[f] + x1*W_es[32+f] + x2*W_es[64+f] + x3*W_es[96+f] + x4*W_es[128+f];
    float vm =           x0*W_ev[f] + x1*W_ev[32+f] + x2*W_ev[64+f] + x3*W_ev[96+f] + x4*W_ev[128+f];
    float v0 = vm*pos[n*3+0], v1 = vm*pos[n*3+1], v2 = vm*pos[n*3+2];
    ns[tid] = s;
    nv[n*96+f*3+0] = v0;
    nv[n*96+f*3+1] = v1;
    nv[n*96+f*3+2] = v2;
    us4 q;
    q[0] = (unsigned short)f2bf_s(s);
    q[1] = (unsigned short)f2bf_s(v0);
    q[2] = (unsigned short)f2bf_s(v1);
    q[3] = (unsigned short)f2bf_s(v2);
    *(us4*)((unsigned short*)nbf + (size_t)n*128 + f*4) = q;
}

// ---------------- fused weight transposes -> bf16 ----------------
__global__ __launch_bounds__(256) void k_transpose(
    const float* __restrict__ W2, __hip_bfloat16* __restrict__ W2bf,
    const float* __restrict__ W_inv, __hip_bfloat16* __restrict__ WinvT)
{
    int tid = blockIdx.x*256 + threadIdx.x;
    if (tid < NLAYERS*6144){
        int l = tid / 6144; int r = tid - l*6144;
        int j = r >> 6; int k = r & 63;
        W2bf[l*6144 + j*64 + k] = __float2bfloat16(W2[l*6144 + k*96 + j]);
    } else if (tid < NLAYERS*6144 + 8192){
        int r = tid - NLAYERS*6144;
        int n = r >> 6, k = r & 63;
        WinvT[n*64 + k] = __float2bfloat16(W_inv[k*128 + n]);
    }
}

// ---------------- edge MLP via MFMA -> bf16 h rows [E][96] (edge-major) ----------------
__global__ __launch_bounds__(256) void k_mlp_mfma(
    const float* __restrict__ ein8,
    const float* __restrict__ W1l, const float* __restrict__ b1l,
    const __hip_bfloat16* __restrict__ W2bfl, const float* __restrict__ b2l,
    __hip_bfloat16* __restrict__ hbuf)
{
    __shared__ __align__(16) __hip_bfloat16 cstage[2][64][104];   // 2 x 13.3 KB
    const int tid  = threadIdx.x;
    const int lane = tid & 63;
    const int wave = tid >> 6;
    const int m    = lane & 15;
    const int quad = lane >> 4;

    for (int t=0; t<TILES; t++){
        const long long blockbase = ((long long)blockIdx.x*TILES + t) * 64;
        const long long edge = blockbase + wave*16 + m;

        const float4* p = (const float4*)(ein8 + edge*8);
        float4 q0 = p[0], q1 = p[1];
        float e0=q0.x, e1=q0.y, e2=q0.z, e3=q0.w, e4=q1.x;

        short8 afrag[2];
        #pragma unroll
        for (int s=0;s<2;s++){
            #pragma unroll
            for (int j=0;j<8;j++){
                int k = s*32 + quad*8 + j;
                float a = b1l[k] + e0*W1l[k] + e1*W1l[64+k] + e2*W1l[128+k]
                                 + e3*W1l[192+k] + e4*W1l[256+k];
                afrag[s][j] = f2bf_s(elu_f(a));
            }
        }

        f32x4 acc[6];
        #pragma unroll
        for (int u=0;u<6;u++) acc[u] = (f32x4){0.f,0.f,0.f,0.f};

        #pragma unroll
        for (int s=0;s<2;s++){
            #pragma unroll
            for (int u=0;u<6;u++){
                int n = u*16 + m;
                short8 bfrag = *(const short8*)(W2bfl + n*64 + s*32 + quad*8);
                acc[u] = __builtin_amdgcn_mfma_f32_16x16x32_bf16(afrag[s], bfrag, acc[u], 0, 0, 0);
            }
        }

        __hip_bfloat16 (*cs)[104] = cstage[t&1];
        #pragma unroll
        for (int u=0;u<6;u++){
            int n = u*16 + m;
            float bias = b2l[n];
            #pragma unroll
            for (int r=0;r<4;r++){
                cs[wave*16 + quad*4 + r][n] = __float2bfloat16(acc[u][r] + bias);
            }
        }
        __syncthreads();

        // cooperative edge-major store: 64 rows x 96 bf16 = 768 16B-chunks
        #pragma unroll
        for (int it=0; it<3; it++){
            int flat = it*256 + tid;
            int e = flat / 12, seg = flat % 12;
            float4 val = *(const float4*)&cs[e][seg*8];
            *(float4*)(hbuf + (blockbase + e)*96 + seg*8) = val;
        }
    }
}

// ---------------- CSR gather-aggregate + node update (no atomics) ----------------
// 32 lanes/node, blocked unroll-4 (R13: k_agg <76 µs at 32 VGPR / 66% occ).
__global__ __launch_bounds__(256) void k_agg(
    const int* __restrict__ rowptr, const int* __restrict__ esrc,
    const float* __restrict__ ein8, const __hip_bfloat16* __restrict__ hbuf,
    float* __restrict__ ns, float* __restrict__ nv,
    const __hip_bfloat16* __restrict__ nbfi,
    const float* __restrict__ Wsl, const float* __restrict__ Wvl,
    __hip_bfloat16* __restrict__ nbfo)
{
    int tid = blockIdx.x*256 + threadIdx.x;
    int n = tid >> 5, f = tid & 31;
    if (n >= NN) return;
    int beg = rowptr[n], end = rowptr[n+1];
    float as=0.f, a0=0.f, a1=0.f, a2=0.f;
    {
        const unsigned short* hb = (const unsigned short*)hbuf;
        const unsigned short* nb = (const unsigned short*)nbfi;
        const int last = end - 1;
        for (int sb=beg; sb<end; sb+=4){
            float4 u[4]; unsigned short hx[4],hy[4],hz[4]; us4 nq[4];
            #pragma unroll
            for (int j=0;j<4;j++){
                int sl = min(sb+j, last);
                u[j] = *(const float4*)(ein8 + (size_t)sl*8 + 4);
                size_t ho = (size_t)sl*96;
                hx[j]=hb[ho+f]; hy[j]=hb[ho+32+f]; hz[j]=hb[ho+64+f];
                nq[j] = *(const us4*)(nb + (size_t)esrc[sl]*128 + f*4);
            }
            #pragma unroll
            for (int j=0;j<4;j++){
                if (sb+j < end){
                    float gs = bf2f(hx[j]), gv = bf2f(hy[j]), gsv = bf2f(hz[j]);
                    float s  = bf2f(nq[j][0]);
                    float v0 = bf2f(nq[j][1]), v1 = bf2f(nq[j][2]), v2 = bf2f(nq[j][3]);
                    float c = gsv*s;
                    as += gs*s;
                    a0 += gv*v0 + c*u[j].y;
                    a1 += gv*v1 + c*u[j].z;
                    a2 += gv*v2 + c*u[j].w;
                }
            }
        }
    }
    float invd = 1.f/fmaxf((float)(end-beg), 1.f);
    as*=invd; a0*=invd; a1*=invd; a2*=invd;
    float os=0.f, o0=0.f, o1=0.f, o2=0.f;
    #pragma unroll
    for (int k=0;k<FF;k++){
        float bs = __shfl(as, k, 32);
        float b0 = __shfl(a0, k, 32);
        float b1 = __shfl(a1, k, 32);
        float b2 = __shfl(a2, k, 32);
        float ws = Wsl[k*32+f];
        float wv = Wvl[k*32+f];
        os += bs*ws; o0 += b0*wv; o1 += b1*wv; o2 += b2*wv;
    }
    float sn = ns[n*32+f] + elu_f(os);
    float w0 = nv[n*96+f*3+0] + o0;
    float w1 = nv[n*96+f*3+1] + o1;
    float w2 = nv[n*96+f*3+2] + o2;
    ns[n*32+f] = sn;
    nv[n*96+f*3+0] = w0;
    nv[n*96+f*3+1] = w1;
    nv[n*96+f*3+2] = w2;
    us4 q;
    q[0] = (unsigned short)f2bf_s(sn);
    q[1] = (unsigned short)f2bf_s(w0);
    q[2] = (unsigned short)f2bf_s(w1);
    q[3] = (unsigned short)f2bf_s(w2);
    *(us4*)((unsigned short*)nbfo + (size_t)n*128 + f*4) = q;
}

// ---------------- invariant map via MFMA: inv[N,128] = feat[N,64] @ W_inv (no bias) ----------------
__global__ __launch_bounds__(256) void k_invgemm(
    const float* __restrict__ ns, const float* __restrict__ nv,
    const __hip_bfloat16* __restrict__ WinvT,   // [128][64] bf16
    float* __restrict__ inv)                    // [N][128] fp32
{
    const int tid  = threadIdx.x;
    const int lane = tid & 63;
    const int wave = tid >> 6;
    const int m    = lane & 15;
    const int quad = lane >> 4;
    const int tilebase = blockIdx.x*64 + wave*16;
    const int node = tilebase + m;
    const bool valid = node < NN;

    short8 afrag[2];
    #pragma unroll
    for (int j=0;j<8;j++){
        int k = quad*8 + j;            // 0..31
        float fs = valid ? ns[(size_t)node*32 + k] : 0.f;
        afrag[0][j] = f2bf_s(fs);
        float v0 = valid ? nv[(size_t)node*96 + k*3+0] : 0.f;
        float v1 = valid ? nv[(size_t)node*96 + k*3+1] : 0.f;
        float v2 = valid ? nv[(size_t)node*96 + k*3+2] : 0.f;
        afrag[1][j] = f2bf_s(sqrtf(v0*v0+v1*v1+v2*v2+EPSF));
    }
    f32x4 acc[8];
    #pragma unroll
    for (int t=0;t<8;t++) acc[t] = (f32x4){0.f,0.f,0.f,0.f};
    #pragma unroll
    for (int s=0;s<2;s++){
        #pragma unroll
        for (int t=0;t<8;t++){
            short8 bfrag = *(const short8*)(WinvT + (t*16+m)*64 + s*32 + quad*8);
            acc[t] = __builtin_amdgcn_mfma_f32_16x16x32_bf16(afrag[s], bfrag, acc[t], 0, 0, 0);
        }
    }
    #pragma unroll
    for (int r=0;r<4;r++){
        int nrow = tilebase + quad*4 + r;
        if (nrow < NN){
            #pragma unroll
            for (int t=0;t<8;t++){
                inv[(size_t)nrow*128 + t*16 + m] = acc[t][r];
            }
        }
    }
}

// ---------------- graph mean pool over inv (binary-search bounds fused in) ----------------
__global__ __launch_bounds__(128) void k_pool(
    const int* __restrict__ batch, const float* __restrict__ inv,
    const float* __restrict__ b_inv, float* __restrict__ xg)
{
    int g = blockIdx.x, j = threadIdx.x;
    int lo = 0, hi = NN;
    while (lo < hi){ int mid=(lo+hi)>>1; if (batch[mid] < g) lo=mid+1; else hi=mid; }
    int beg = lo;
    lo = 0; hi = NN;
    while (lo < hi){ int mid=(lo+hi)>>1; if (batch[mid] < g+1) lo=mid+1; else hi=mid; }
    int end = lo;
    float acc = 0.f;
    for (int n=beg; n<end; n++) acc += inv[(size_t)n*128 + j];
    int cnt = end - beg;
    float cp = fmaxf((float)cnt, 1.f);
    xg[g*128+j] = acc/cp + b_inv[j]*((float)cnt/cp);
}

// ---------------- per-column mean/rstd over G rows ----------------
__global__ __launch_bounds__(256) void k_colstats(
    const float* __restrict__ in, float* __restrict__ mean, float* __restrict__ rstd)
{
    int j = blockIdx.x;
    float s=0.f, q=0.f;
    for (int g=threadIdx.x; g<GG; g+=256){
        float x = in[g*128+j];
        s += x; q += x*x;
    }
    __shared__ float rs[256], rq[256];
    rs[threadIdx.x]=s; rq[threadIdx.x]=q;
    __syncthreads();
    for (int st=128; st>0; st>>=1){
        if (threadIdx.x < st){ rs[threadIdx.x]+=rs[threadIdx.x+st]; rq[threadIdx.x]+=rq[threadIdx.x+st]; }
        __syncthreads();
    }
    if (threadIdx.x==0){
        float m = rs[0]/(float)GG;
        float v = rq[0]/(float)GG - m*m;
        mean[j]=m; rstd[j]=rsqrtf(v+1e-5f);
    }
}

// ---------------- BN1 + ELU + FC1 ----------------
__global__ __launch_bounds__(128) void k_fc1(
    const float* __restrict__ xg, const float* __restrict__ mean, const float* __restrict__ rstd,
    const float* __restrict__ g1, const float* __restrict__ be1,
    const float* __restrict__ Wf1, const float* __restrict__ bf1,
    float* __restrict__ z1)
{
    int g = blockIdx.x, j = threadIdx.x;
    __shared__ float a[128];
    float xin = xg[g*128+j];
    a[j] = elu_f((xin-mean[j])*rstd[j]*g1[j]+be1[j]);
    __syncthreads();
    float z = bf1[j];
    #pragma unroll 8
    for (int k=0;k<128;k++) z += a[k]*Wf1[k*128+j];
    z1[g*128+j] = z;
}

// ---------------- BN2 + ELU + FC2 -> out ----------------
__global__ __launch_bounds__(128) void k_out(
    const float* __restrict__ z1, const float* __restrict__ mean, const float* __restrict__ rstd,
    const float* __restrict__ g2, const float* __restrict__ be2,
    const float* __restrict__ Wf2, const float* __restrict__ bf2,
    float* __restrict__ out)
{
    int g = blockIdx.x, j = threadIdx.x;
    float a = elu_f((z1[g*128+j]-mean[j])*rstd[j]*g2[j]+be2[j]) * Wf2[j];
    __shared__ float red[128];
    red[j]=a; __syncthreads();
    for (int st=64; st>0; st>>=1){
        if (j<st) red[j]+=red[j+st];
        __syncthreads();
    }
    if (j==0) out[g] = red[0] + bf2[0];
}

extern "C" void kernel_launch(void* const* d_in, const int* in_sizes, int n_in,
                              void* d_out, int out_size, void* d_ws, size_t ws_size,
                              hipStream_t stream)
{
    const float* x      = (const float*)d_in[0];
    const float* pos    = (const float*)d_in[1];
    const int*   ei     = (const int*)d_in[2];
    const float* eattr  = (const float*)d_in[3];
    const int*   batch  = (const int*)d_in[4];
    const float* W_es   = (const float*)d_in[5];
    const float* b_es   = (const float*)d_in[6];
    const float* W_ev   = (const float*)d_in[7];
    const float* W1     = (const float*)d_in[8];
    const float* b1     = (const float*)d_in[9];
    const float* W2     = (const float*)d_in[10];
    const float* b2     = (const float*)d_in[11];
    const float* Ws     = (const float*)d_in[12];
    const float* Wv     = (const float*)d_in[13];
    const float* W_inv  = (const float*)d_in[14];
    const float* b_inv  = (const float*)d_in[15];
    const float* g1     = (const float*)d_in[16];
    const float* be1    = (const float*)d_in[17];
    const float* Wf1    = (const float*)d_in[18];
    const float* bf1    = (const float*)d_in[19];
    const float* g2     = (const float*)d_in[20];
    const float* be2    = (const float*)d_in[21];
    const float* Wf2    = (const float*)d_in[22];
    const float* bf2    = (const float*)d_in[23];
    float* out = (float*)d_out;

    // ---- workspace layout (4-byte units, 64B aligned blocks) ----
    // Total ~236.4 MB (< ~256 MiB ws_size; R7 lesson). inv aliases hbuf.
    char* base = (char*)d_ws;
    size_t off = 0;
    auto alloc = [&](size_t elems4) { // elems in 4-byte units
        void* p = base + off;
        off += ((elems4*4 + 63) & ~size_t(63));
        return p;
    };
    int*   counts = (int*)  alloc(50000);       // zeroed
    int*   cursor = (int*)  alloc(50000);       // zeroed
    size_t zero_bytes = off;
    int*   rowptr = (int*)  alloc(50001);
    int*   bsum   = (int*)  alloc(SCAN_BLOCKS);
    int*   boff   = (int*)  alloc(SCAN_BLOCKS);
    int*   esrc   = (int*)  alloc(800000);
    float* ein8   = (float*)alloc(6400000);     // [E][8]: d,a0..a3 | a3,u0,u1,u2
    float* ns     = (float*)alloc(1600000);     // fp32 master, in-place residual
    float* nv     = (float*)alloc(4800000);
    __hip_bfloat16* nbfA = (__hip_bfloat16*)alloc(3200000); // [N][32][4] bf16 quads = 12.8 MB
    __hip_bfloat16* nbfB = (__hip_bfloat16*)alloc(3200000);
    __hip_bfloat16* W2bf = (__hip_bfloat16*)alloc(12288);   // NL*96*64 bf16
    __hip_bfloat16* WinvT= (__hip_bfloat16*)alloc(4096);    // [128][64] bf16
    float* xg     = (float*)alloc(262144);
    float* z1     = (float*)alloc(262144);
    float* m1     = (float*)alloc(128);
    float* r1     = (float*)alloc(128);
    float* m2     = (float*)alloc(128);
    float* r2     = (float*)alloc(128);
    __hip_bfloat16* hbuf = (__hip_bfloat16*)alloc(38400000); // [E][96] bf16 edge-major
    float* inv    = (float*)hbuf;               // alias: used only after layers

    hipMemsetAsync(d_ws, 0, zero_bytes, stream);

    // ---- setup: CSR build (3-phase parallel scan) + embedding + transposes ----
    k_count    <<<EE/256, 256, 0, stream>>>(ei, counts);
    k_bsum     <<<SCAN_BLOCKS, 256, 0, stream>>>(counts, bsum);
    k_bscan    <<<1, 256, 0, stream>>>(bsum, boff, rowptr + NN);
    k_rowptr   <<<SCAN_BLOCKS, 256, 0, stream>>>(counts, boff, rowptr);
    k_fill     <<<EE/256, 256, 0, stream>>>(ei, pos, eattr, rowptr, cursor, esrc, ein8);
    k_embed    <<<NN*FF/256, 256, 0, stream>>>(x, pos, W_es, b_es, W_ev, ns, nv, nbfA);
    k_transpose<<<(NLAYERS*6144+8192+255)/256, 256, 0, stream>>>(W2, W2bf, W_inv, WinvT);

    // ---- message-passing layers (bf16 gather copy double-buffered) ----
    for (int l=0; l<NLAYERS; l++){
        const __hip_bfloat16* nbfi = (l&1) ? nbfB : nbfA;
        __hip_bfloat16* nbfo = (l&1) ? nbfA : nbfB;
        k_mlp_mfma<<<EE/(64*TILES), 256, 0, stream>>>(ein8,
            W1 + l*320, b1 + l*64, W2bf + l*6144, b2 + l*96, hbuf);
        k_agg<<<(NN*32+255)/256, 256, 0, stream>>>(rowptr, esrc, ein8, hbuf,
            ns, nv, nbfi, Ws + l*1024, Wv + l*1024, nbfo);
    }
    // fp32 ns/nv hold final node features (in-place updates)

    // ---- invariant map (MFMA) + pooling + head ----
    k_invgemm <<<(NN+63)/64, 256, 0, stream>>>(ns, nv, WinvT, inv);
    k_pool    <<<GG, 128, 0, stream>>>(batch, inv, b_inv, xg);
    k_colstats<<<128, 256, 0, stream>>>(xg, m1, r1);
    k_fc1     <<<GG, 128, 0, stream>>>(xg, m1, r1, g1, be1, Wf1, bf1, z1);
    k_colstats<<<128, 256, 0, stream>>>(z1, m2, r2);
    k_out     <<<GG, 128, 0, stream>>>(z1, m2, r2, g2, be2, Wf2, bf2, out);
}

// Round 15
// 806.537 us; speedup vs baseline: 1.5508x; 1.0123x over previous
//
#include <hip/hip_runtime.h>
#include <hip/hip_bf16.h>
#include <math.h>

#define NN 50000
#define EE 800000
#define FF 32
#define HH 64
#define GG 2048
#define NLAYERS 4
#define EPSF 1e-6f
#define TILES 4
#define SCAN_BLOCKS ((NN + 255) / 256)   // 196

typedef __attribute__((ext_vector_type(8))) short short8;
typedef __attribute__((ext_vector_type(4))) float f32x4;
typedef __attribute__((ext_vector_type(4))) unsigned short us4;

__device__ __forceinline__ float elu_f(float x){ return x > 0.0f ? x : __expf(x) - 1.0f; }
__device__ __forceinline__ short f2bf_s(float x){
    __hip_bfloat16 h = __float2bfloat16(x);
    return *reinterpret_cast<short*>(&h);
}
__device__ __forceinline__ float bf2f(unsigned short u){
    unsigned int w = ((unsigned int)u) << 16;
    return *reinterpret_cast<float*>(&w);
}

// ---------------- in-degree count ----------------
__global__ __launch_bounds__(256) void k_count(const int* __restrict__ ei, int* __restrict__ counts)
{
    int e = blockIdx.x*256 + threadIdx.x;
    if (e >= EE) return;
    atomicAdd(&counts[ei[EE+e]], 1);
}

// ---------------- parallel scan phase 1: per-block sums ----------------
__global__ __launch_bounds__(256) void k_bsum(const int* __restrict__ counts, int* __restrict__ bsum)
{
    int i = blockIdx.x*256 + threadIdx.x;
    int v = (i < NN) ? counts[i] : 0;
    #pragma unroll
    for (int o=32; o>0; o>>=1) v += __shfl_down(v, o, 64);
    __shared__ int ws[4];
    if ((threadIdx.x & 63) == 0) ws[threadIdx.x >> 6] = v;
    __syncthreads();
    if (threadIdx.x == 0) bsum[blockIdx.x] = ws[0]+ws[1]+ws[2]+ws[3];
}

// ---------------- parallel scan phase 2: scan block sums (1 tiny block) ----------------
__global__ __launch_bounds__(256) void k_bscan(const int* __restrict__ bsum, int* __restrict__ boff,
                                               int* __restrict__ rowptr_last)
{
    int t = threadIdx.x;
    int v = (t < SCAN_BLOCKS) ? bsum[t] : 0;
    __shared__ int sh[256];
    sh[t] = v; __syncthreads();
    for (int o=1; o<256; o<<=1){
        int u = (t >= o) ? sh[t-o] : 0;
        __syncthreads();
        sh[t] += u;
        __syncthreads();
    }
    if (t < SCAN_BLOCKS) boff[t] = sh[t] - v;    // exclusive
    if (t == 255) rowptr_last[0] = sh[255];      // rowptr[NN] = total
}

// ---------------- parallel scan phase 3: per-block exclusive scan + offset ----------------
__global__ __launch_bounds__(256) void k_rowptr(const int* __restrict__ counts,
                                                const int* __restrict__ boff, int* __restrict__ rowptr)
{
    int i = blockIdx.x*256 + threadIdx.x;
    int t = threadIdx.x;
    int v = (i < NN) ? counts[i] : 0;
    __shared__ int sh[256];
    sh[t] = v; __syncthreads();
    for (int o=1; o<256; o<<=1){
        int u = (t >= o) ? sh[t-o] : 0;
        __syncthreads();
        sh[t] += u;
        __syncthreads();
    }
    if (i < NN) rowptr[i] = boff[blockIdx.x] + sh[t] - v;
}

// ---------------- CSR fill: geometry + edge inputs in dst-sorted order ----------------
__global__ __launch_bounds__(256) void k_fill(
    const int* __restrict__ ei, const float* __restrict__ pos, const float* __restrict__ eattr,
    const int* __restrict__ rowptr, int* __restrict__ cursor,
    int* __restrict__ esrc, float* __restrict__ ein8)
{
    int e = blockIdx.x*256 + threadIdx.x;
    if (e >= EE) return;
    int src = ei[e], dst = ei[EE+e];
    float dx = pos[dst*3+0]-pos[src*3+0];
    float dy = pos[dst*3+1]-pos[src*3+1];
    float dz = pos[dst*3+2]-pos[src*3+2];
    float d = sqrtf(dx*dx+dy*dy+dz*dz+EPSF);
    float inv = 1.0f/d;
    int slot = rowptr[dst] + atomicAdd(&cursor[dst], 1);
    esrc[slot] = src;
    float4* p = (float4*)(ein8 + (size_t)slot*8);
    p[0] = make_float4(d, eattr[e*4+0], eattr[e*4+1], eattr[e*4+2]);
    p[1] = make_float4(eattr[e*4+3], dx*inv, dy*inv, dz*inv);
}

// ---------------- node embedding (fp32 master + packed bf16 quad gather copy) ----------------
__global__ __launch_bounds__(256) void k_embed(
    const float* __restrict__ x, const float* __restrict__ pos,
    const float* __restrict__ W_es, const float* __restrict__ b_es,
    const float* __restrict__ W_ev,
    float* __restrict__ ns, float* __restrict__ nv, __hip_bfloat16* __restrict__ nbf)
{
    int tid = blockIdx.x*256 + threadIdx.x;
    if (tid >= NN*FF) return;
    int n = tid >> 5, f = tid & 31;
    float x0=x[n*5+0], x1=x[n*5+1], x2=x[n*5+2], x3=x[n*5+3], x4=x[n*5+4];
    float s  = b_es[f] + x0*W_es[f] + x1*W_es[32+f] + x2*W_es[64+f] + x3*W_es[96+f] + x4*W_es[128+f];
    float vm =           x0*W_ev[f] + x1*W_ev[32+f] + x2*W_ev[64+f] + x3*W_ev[96+f] + x4*W_ev[128+f];
    float v0 = vm*pos[n*3+0], v1 = vm*pos[n*3+1], v2 = vm*pos[n*3+2];
    ns[tid] = s;
    nv[n*96+f*3+0] = v0;
    nv[n*96+f*3+1] = v1;
    nv[n*96+f*3+2] = v2;
    us4 q;
    q[0] = (unsigned short)f2bf_s(s);
    q[1] = (unsigned short)f2bf_s(v0);
    q[2] = (unsigned short)f2bf_s(v1);
    q[3] = (unsigned short)f2bf_s(v2);
    *(us4*)((unsigned short*)nbf + (size_t)n*128 + f*4) = q;
}

// ---------------- fused weight transposes -> bf16 ----------------
__global__ __launch_bounds__(256) void k_transpose(
    const float* __restrict__ W2, __hip_bfloat16* __restrict__ W2bf,
    const float* __restrict__ W_inv, __hip_bfloat16* __restrict__ WinvT)
{
    int tid = blockIdx.x*256 + threadIdx.x;
    if (tid < NLAYERS*6144){
        int l = tid / 6144; int r = tid - l*6144;
        int j = r >> 6; int k = r & 63;
        W2bf[l*6144 + j*64 + k] = __float2bfloat16(W2[l*6144 + k*96 + j]);
    } else if (tid < NLAYERS*6144 + 8192){
        int r = tid - NLAYERS*6144;
        int n = r >> 6, k = r & 63;
        WinvT[n*64 + k] = __float2bfloat16(W_inv[k*128 + n]);
    }
}

// ---------------- edge MLP via MFMA -> bf16 h rows [E][96] (edge-major) ----------------
__global__ __launch_bounds__(256) void k_mlp_mfma(
    const float* __restrict__ ein8,
    const float* __restrict__ W1l, const float* __restrict__ b1l,
    const __hip_bfloat16* __restrict__ W2bfl, const float* __restrict__ b2l,
    __hip_bfloat16* __restrict__ hbuf)
{
    __shared__ __align__(16) __hip_bfloat16 cstage[2][64][104];   // 2 x 13.3 KB
    const int tid  = threadIdx.x;
    const int lane = tid & 63;
    const int wave = tid >> 6;
    const int m    = lane & 15;
    const int quad = lane >> 4;

    for (int t=0; t<TILES; t++){
        const long long blockbase = ((long long)blockIdx.x*TILES + t) * 64;
        const long long edge = blockbase + wave*16 + m;

        const float4* p = (const float4*)(ein8 + edge*8);
        float4 q0 = p[0], q1 = p[1];
        float e0=q0.x, e1=q0.y, e2=q0.z, e3=q0.w, e4=q1.x;

        short8 afrag[2];
        #pragma unroll
        for (int s=0;s<2;s++){
            #pragma unroll
            for (int j=0;j<8;j++){
                int k = s*32 + quad*8 + j;
                float a = b1l[k] + e0*W1l[k] + e1*W1l[64+k] + e2*W1l[128+k]
                                 + e3*W1l[192+k] + e4*W1l[256+k];
                afrag[s][j] = f2bf_s(elu_f(a));
            }
        }

        f32x4 acc[6];
        #pragma unroll
        for (int u=0;u<6;u++) acc[u] = (f32x4){0.f,0.f,0.f,0.f};

        #pragma unroll
        for (int s=0;s<2;s++){
            #pragma unroll
            for (int u=0;u<6;u++){
                int n = u*16 + m;
                short8 bfrag = *(const short8*)(W2bfl + n*64 + s*32 + quad*8);
                acc[u] = __builtin_amdgcn_mfma_f32_16x16x32_bf16(afrag[s], bfrag, acc[u], 0, 0, 0);
            }
        }

        __hip_bfloat16 (*cs)[104] = cstage[t&1];
        #pragma unroll
        for (int u=0;u<6;u++){
            int n = u*16 + m;
            float bias = b2l[n];
            #pragma unroll
            for (int r=0;r<4;r++){
                cs[wave*16 + quad*4 + r][n] = __float2bfloat16(acc[u][r] + bias);
            }
        }
        __syncthreads();

        // cooperative edge-major store: 64 rows x 96 bf16 = 768 16B-chunks
        #pragma unroll
        for (int it=0; it<3; it++){
            int flat = it*256 + tid;
            int e = flat / 12, seg = flat % 12;
            float4 val = *(const float4*)&cs[e][seg*8];
            *(float4*)(hbuf + (blockbase + e)*96 + seg*8) = val;
        }
    }
}

// ---------------- CSR gather-aggregate + node update (no atomics) ----------------
// 32 lanes/node, blocked unroll-4 + esrc PREFETCHED ONE GROUP AHEAD: breaks
// the esrc->nbf 2-hop chain (R14 post-mortem: same-group esrc+nq issue meant
// nq waited ~200-500cyc on esrc). src indices are resolved a full iteration
// early, so all 4 nq gathers issue at group start. +8 VGPR (~40 total).
__global__ __launch_bounds__(256) void k_agg(
    const int* __restrict__ rowptr, const int* __restrict__ esrc,
    const float* __restrict__ ein8, const __hip_bfloat16* __restrict__ hbuf,
    float* __restrict__ ns, float* __restrict__ nv,
    const __hip_bfloat16* __restrict__ nbfi,
    const float* __restrict__ Wsl, const float* __restrict__ Wvl,
    __hip_bfloat16* __restrict__ nbfo)
{
    int tid = blockIdx.x*256 + threadIdx.x;
    int n = tid >> 5, f = tid & 31;
    if (n >= NN) return;
    int beg = rowptr[n], end = rowptr[n+1];
    float as=0.f, a0=0.f, a1=0.f, a2=0.f;
    if (beg < end){
        const unsigned short* hb = (const unsigned short*)hbuf;
        const unsigned short* nb = (const unsigned short*)nbfi;
        const int last = end - 1;
        // prefetch esrc for the first group
        int srcs[4];
        #pragma unroll
        for (int j=0;j<4;j++) srcs[j] = esrc[min(beg+j, last)];
        for (int sb=beg; sb<end; sb+=4){
            // prefetch esrc for the NEXT group (independent of this group's loads)
            int srcsN[4];
            #pragma unroll
            for (int j=0;j<4;j++) srcsN[j] = esrc[min(sb+4+j, last)];
            // issue all loads for this group; src already resolved
            float4 u[4]; unsigned short hx[4],hy[4],hz[4]; us4 nq[4];
            #pragma unroll
            for (int j=0;j<4;j++){
                int sl = min(sb+j, last);
                u[j] = *(const float4*)(ein8 + (size_t)sl*8 + 4);
                size_t ho = (size_t)sl*96;
                hx[j]=hb[ho+f]; hy[j]=hb[ho+32+f]; hz[j]=hb[ho+64+f];
                nq[j] = *(const us4*)(nb + (size_t)srcs[j]*128 + f*4);
            }
            #pragma unroll
            for (int j=0;j<4;j++){
                if (sb+j < end){
                    float gs = bf2f(hx[j]), gv = bf2f(hy[j]), gsv = bf2f(hz[j]);
                    float s  = bf2f(nq[j][0]);
                    float v0 = bf2f(nq[j][1]), v1 = bf2f(nq[j][2]), v2 = bf2f(nq[j][3]);
                    float c = gsv*s;
                    as += gs*s;
                    a0 += gv*v0 + c*u[j].y;
                    a1 += gv*v1 + c*u[j].z;
                    a2 += gv*v2 + c*u[j].w;
                }
            }
            #pragma unroll
            for (int j=0;j<4;j++) srcs[j] = srcsN[j];
        }
    }
    float invd = 1.f/fmaxf((float)(end-beg), 1.f);
    as*=invd; a0*=invd; a1*=invd; a2*=invd;
    float os=0.f, o0=0.f, o1=0.f, o2=0.f;
    #pragma unroll
    for (int k=0;k<FF;k++){
        float bs = __shfl(as, k, 32);
        float b0 = __shfl(a0, k, 32);
        float b1 = __shfl(a1, k, 32);
        float b2 = __shfl(a2, k, 32);
        float ws = Wsl[k*32+f];
        float wv = Wvl[k*32+f];
        os += bs*ws; o0 += b0*wv; o1 += b1*wv; o2 += b2*wv;
    }
    float sn = ns[n*32+f] + elu_f(os);
    float w0 = nv[n*96+f*3+0] + o0;
    float w1 = nv[n*96+f*3+1] + o1;
    float w2 = nv[n*96+f*3+2] + o2;
    ns[n*32+f] = sn;
    nv[n*96+f*3+0] = w0;
    nv[n*96+f*3+1] = w1;
    nv[n*96+f*3+2] = w2;
    us4 q;
    q[0] = (unsigned short)f2bf_s(sn);
    q[1] = (unsigned short)f2bf_s(w0);
    q[2] = (unsigned short)f2bf_s(w1);
    q[3] = (unsigned short)f2bf_s(w2);
    *(us4*)((unsigned short*)nbfo + (size_t)n*128 + f*4) = q;
}

// ---------------- invariant map via MFMA: inv[N,128] = feat[N,64] @ W_inv (no bias) ----------------
__global__ __launch_bounds__(256) void k_invgemm(
    const float* __restrict__ ns, const float* __restrict__ nv,
    const __hip_bfloat16* __restrict__ WinvT,   // [128][64] bf16
    float* __restrict__ inv)                    // [N][128] fp32
{
    const int tid  = threadIdx.x;
    const int lane = tid & 63;
    const int wave = tid >> 6;
    const int m    = lane & 15;
    const int quad = lane >> 4;
    const int tilebase = blockIdx.x*64 + wave*16;
    const int node = tilebase + m;
    const bool valid = node < NN;

    short8 afrag[2];
    #pragma unroll
    for (int j=0;j<8;j++){
        int k = quad*8 + j;            // 0..31
        float fs = valid ? ns[(size_t)node*32 + k] : 0.f;
        afrag[0][j] = f2bf_s(fs);
        float v0 = valid ? nv[(size_t)node*96 + k*3+0] : 0.f;
        float v1 = valid ? nv[(size_t)node*96 + k*3+1] : 0.f;
        float v2 = valid ? nv[(size_t)node*96 + k*3+2] : 0.f;
        afrag[1][j] = f2bf_s(sqrtf(v0*v0+v1*v1+v2*v2+EPSF));
    }
    f32x4 acc[8];
    #pragma unroll
    for (int t=0;t<8;t++) acc[t] = (f32x4){0.f,0.f,0.f,0.f};
    #pragma unroll
    for (int s=0;s<2;s++){
        #pragma unroll
        for (int t=0;t<8;t++){
            short8 bfrag = *(const short8*)(WinvT + (t*16+m)*64 + s*32 + quad*8);
            acc[t] = __builtin_amdgcn_mfma_f32_16x16x32_bf16(afrag[s], bfrag, acc[t], 0, 0, 0);
        }
    }
    #pragma unroll
    for (int r=0;r<4;r++){
        int nrow = tilebase + quad*4 + r;
        if (nrow < NN){
            #pragma unroll
            for (int t=0;t<8;t++){
                inv[(size_t)nrow*128 + t*16 + m] = acc[t][r];
            }
        }
    }
}

// ---------------- graph mean pool over inv (binary-search bounds fused in) ----------------
__global__ __launch_bounds__(128) void k_pool(
    const int* __restrict__ batch, const float* __restrict__ inv,
    const float* __restrict__ b_inv, float* __restrict__ xg)
{
    int g = blockIdx.x, j = threadIdx.x;
    int lo = 0, hi = NN;
    while (lo < hi){ int mid=(lo+hi)>>1; if (batch[mid] < g) lo=mid+1; else hi=mid; }
    int beg = lo;
    lo = 0; hi = NN;
    while (lo < hi){ int mid=(lo+hi)>>1; if (batch[mid] < g+1) lo=mid+1; else hi=mid; }
    int end = lo;
    float acc = 0.f;
    for (int n=beg; n<end; n++) acc += inv[(size_t)n*128 + j];
    int cnt = end - beg;
    float cp = fmaxf((float)cnt, 1.f);
    xg[g*128+j] = acc/cp + b_inv[j]*((float)cnt/cp);
}

// ---------------- per-column mean/rstd over G rows ----------------
__global__ __launch_bounds__(256) void k_colstats(
    const float* __restrict__ in, float* __restrict__ mean, float* __restrict__ rstd)
{
    int j = blockIdx.x;
    float s=0.f, q=0.f;
    for (int g=threadIdx.x; g<GG; g+=256){
        float x = in[g*128+j];
        s += x; q += x*x;
    }
    __shared__ float rs[256], rq[256];
    rs[threadIdx.x]=s; rq[threadIdx.x]=q;
    __syncthreads();
    for (int st=128; st>0; st>>=1){
        if (threadIdx.x < st){ rs[threadIdx.x]+=rs[threadIdx.x+st]; rq[threadIdx.x]+=rq[threadIdx.x+st]; }
        __syncthreads();
    }
    if (threadIdx.x==0){
        float m = rs[0]/(float)GG;
        float v = rq[0]/(float)GG - m*m;
        mean[j]=m; rstd[j]=rsqrtf(v+1e-5f);
    }
}

// ---------------- BN1 + ELU + FC1 ----------------
__global__ __launch_bounds__(128) void k_fc1(
    const float* __restrict__ xg, const float* __restrict__ mean, const float* __restrict__ rstd,
    const float* __restrict__ g1, const float* __restrict__ be1,
    const float* __restrict__ Wf1, const float* __restrict__ bf1,
    float* __restrict__ z1)
{
    int g = blockIdx.x, j = threadIdx.x;
    __shared__ float a[128];
    float xin = xg[g*128+j];
    a[j] = elu_f((xin-mean[j])*rstd[j]*g1[j]+be1[j]);
    __syncthreads();
    float z = bf1[j];
    #pragma unroll 8
    for (int k=0;k<128;k++) z += a[k]*Wf1[k*128+j];
    z1[g*128+j] = z;
}

// ---------------- BN2 + ELU + FC2 -> out ----------------
__global__ __launch_bounds__(128) void k_out(
    const float* __restrict__ z1, const float* __restrict__ mean, const float* __restrict__ rstd,
    const float* __restrict__ g2, const float* __restrict__ be2,
    const float* __restrict__ Wf2, const float* __restrict__ bf2,
    float* __restrict__ out)
{
    int g = blockIdx.x, j = threadIdx.x;
    float a = elu_f((z1[g*128+j]-mean[j])*rstd[j]*g2[j]+be2[j]) * Wf2[j];
    __shared__ float red[128];
    red[j]=a; __syncthreads();
    for (int st=64; st>0; st>>=1){
        if (j<st) red[j]+=red[j+st];
        __syncthreads();
    }
    if (j==0) out[g] = red[0] + bf2[0];
}

extern "C" void kernel_launch(void* const* d_in, const int* in_sizes, int n_in,
                              void* d_out, int out_size, void* d_ws, size_t ws_size,
                              hipStream_t stream)
{
    const float* x      = (const float*)d_in[0];
    const float* pos    = (const float*)d_in[1];
    const int*   ei     = (const int*)d_in[2];
    const float* eattr  = (const float*)d_in[3];
    const int*   batch  = (const int*)d_in[4];
    const float* W_es   = (const float*)d_in[5];
    const float* b_es   = (const float*)d_in[6];
    const float* W_ev   = (const float*)d_in[7];
    const float* W1     = (const float*)d_in[8];
    const float* b1     = (const float*)d_in[9];
    const float* W2     = (const float*)d_in[10];
    const float* b2     = (const float*)d_in[11];
    const float* Ws     = (const float*)d_in[12];
    const float* Wv     = (const float*)d_in[13];
    const float* W_inv  = (const float*)d_in[14];
    const float* b_inv  = (const float*)d_in[15];
    const float* g1     = (const float*)d_in[16];
    const float* be1    = (const float*)d_in[17];
    const float* Wf1    = (const float*)d_in[18];
    const float* bf1    = (const float*)d_in[19];
    const float* g2     = (const float*)d_in[20];
    const float* be2    = (const float*)d_in[21];
    const float* Wf2    = (const float*)d_in[22];
    const float* bf2    = (const float*)d_in[23];
    float* out = (float*)d_out;

    // ---- workspace layout (4-byte units, 64B aligned blocks) ----
    // Total ~236.4 MB (< ~256 MiB ws_size; R7 lesson). inv aliases hbuf.
    char* base = (char*)d_ws;
    size_t off = 0;
    auto alloc = [&](size_t elems4) { // elems in 4-byte units
        void* p = base + off;
        off += ((elems4*4 + 63) & ~size_t(63));
        return p;
    };
    int*   counts = (int*)  alloc(50000);       // zeroed
    int*   cursor = (int*)  alloc(50000);       // zeroed
    size_t zero_bytes = off;
    int*   rowptr = (int*)  alloc(50001);
    int*   bsum   = (int*)  alloc(SCAN_BLOCKS);
    int*   boff   = (int*)  alloc(SCAN_BLOCKS);
    int*   esrc   = (int*)  alloc(800000);
    float* ein8   = (float*)alloc(6400000);     // [E][8]: d,a0..a3 | a3,u0,u1,u2
    float* ns     = (float*)alloc(1600000);     // fp32 master, in-place residual
    float* nv     = (float*)alloc(4800000);
    __hip_bfloat16* nbfA = (__hip_bfloat16*)alloc(3200000); // [N][32][4] bf16 quads = 12.8 MB
    __hip_bfloat16* nbfB = (__hip_bfloat16*)alloc(3200000);
    __hip_bfloat16* W2bf = (__hip_bfloat16*)alloc(12288);   // NL*96*64 bf16
    __hip_bfloat16* WinvT= (__hip_bfloat16*)alloc(4096);    // [128][64] bf16
    float* xg     = (float*)alloc(262144);
    float* z1     = (float*)alloc(262144);
    float* m1     = (float*)alloc(128);
    float* r1     = (float*)alloc(128);
    float* m2     = (float*)alloc(128);
    float* r2     = (float*)alloc(128);
    __hip_bfloat16* hbuf = (__hip_bfloat16*)alloc(38400000); // [E][96] bf16 edge-major
    float* inv    = (float*)hbuf;               // alias: used only after layers

    hipMemsetAsync(d_ws, 0, zero_bytes, stream);

    // ---- setup: CSR build (3-phase parallel scan) + embedding + transposes ----
    k_count    <<<EE/256, 256, 0, stream>>>(ei, counts);
    k_bsum     <<<SCAN_BLOCKS, 256, 0, stream>>>(counts, bsum);
    k_bscan    <<<1, 256, 0, stream>>>(bsum, boff, rowptr + NN);
    k_rowptr   <<<SCAN_BLOCKS, 256, 0, stream>>>(counts, boff, rowptr);
    k_fill     <<<EE/256, 256, 0, stream>>>(ei, pos, eattr, rowptr, cursor, esrc, ein8);
    k_embed    <<<NN*FF/256, 256, 0, stream>>>(x, pos, W_es, b_es, W_ev, ns, nv, nbfA);
    k_transpose<<<(NLAYERS*6144+8192+255)/256, 256, 0, stream>>>(W2, W2bf, W_inv, WinvT);

    // ---- message-passing layers (bf16 gather copy double-buffered) ----
    for (int l=0; l<NLAYERS; l++){
        const __hip_bfloat16* nbfi = (l&1) ? nbfB : nbfA;
        __hip_bfloat16* nbfo = (l&1) ? nbfA : nbfB;
        k_mlp_mfma<<<EE/(64*TILES), 256, 0, stream>>>(ein8,
            W1 + l*320, b1 + l*64, W2bf + l*6144, b2 + l*96, hbuf);
        k_agg<<<(NN*32+255)/256, 256, 0, stream>>>(rowptr, esrc, ein8, hbuf,
            ns, nv, nbfi, Ws + l*1024, Wv + l*1024, nbfo);
    }
    // fp32 ns/nv hold final node features (in-place updates)

    // ---- invariant map (MFMA) + pooling + head ----
    k_invgemm <<<(NN+63)/64, 256, 0, stream>>>(ns, nv, WinvT, inv);
    k_pool    <<<GG, 128, 0, stream>>>(batch, inv, b_inv, xg);
    k_colstats<<<128, 256, 0, stream>>>(xg, m1, r1);
    k_fc1     <<<GG, 128, 0, stream>>>(xg, m1, r1, g1, be1, Wf1, bf1, z1);
    k_colstats<<<128, 256, 0, stream>>>(z1, m2, r2);
    k_out     <<<GG, 128, 0, stream>>>(z1, m2, r2, g2, be2, Wf2, bf2, out);
}